// Round 2
// baseline (1837.886 us; speedup 1.0000x reference)
//
#include <hip/hip_runtime.h>
#include <hip/hip_bf16.h>

#define NB 2
#define NC 256
#define NH 120
#define NW 240
#define NWH 121
#define NHW (NH*NW)       // 28800
#define NHWF (NH*NWH)     // 14520
#define NHID 512
#define REPS 1e-5f
#define SC_W 0.06454972243679028f   // 1/sqrt(240)
#define SC_H 0.09128709291752769f   // 1/sqrt(120)

typedef __hip_bfloat16 bf16;

__device__ __forceinline__ float b2f(bf16 v){ return __bfloat162float(v); }
__device__ __forceinline__ float gelu_f(float x){ return 0.5f*x*(1.f+erff(x*0.7071067811865476f)); }

// workspace float offsets
#define OFF_A0  0
#define OFF_D0  512
#define OFF_A1  1024
#define OFF_D1  1536
#define OFF_TWT 2048        // float2[240*121]  cos/sin, w-major
#define OFF_TW2 60128       // float2[121*240]  cos/sin, k-major
#define OFF_THT 118208      // float2[120*120]
#define OFF_IWT 147008      // float[256*256]   inner_w^T  [i][o]
#define OFF_W1T 212544      // float[256*512]   mlp_w1^T   [i][o]
#define OFF_W2T 343616      // float[512*256]   mlp_w2^T   [i][o]
#define OFF_FRE 474688      // float[2*256*120*121]
#define OFF_FIM 7908928
#define OFF_GRE 15343168
#define OFF_GIM 22777408
#define OFF_S   30211648    // float[2*256*28800]
#define OFF_HD  44957248    // bf16[2*512*28800] = 14745600 float slots
#define WS_FLOATS_NEEDED 59702848ULL   // ~238.8 MB, confirmed fits (round 1 kernels ran)

// ---------------- setup: twiddle tables + weight transposes ----------------
__global__ __launch_bounds__(256) void k_setup(float* ws, const float* iw, const float* w1, const float* w2){
  int t = blockIdx.x*256 + threadIdx.x;
  const float PI2 = 6.283185307179586f;
  if (t < 29040){ // Twt[w][k]
    int w = t/NWH, k = t - w*NWH;
    float ang = PI2 * (float)((w*k) % NW) / (float)NW;
    float s,c; sincosf(ang,&s,&c);
    ((float2*)(ws+OFF_TWT))[t] = make_float2(c,s);
    return;
  } t -= 29040;
  if (t < 29040){ // Tw2[k][w]
    int k = t/NW, w = t - k*NW;
    float ang = PI2 * (float)((w*k) % NW) / (float)NW;
    float s,c; sincosf(ang,&s,&c);
    ((float2*)(ws+OFF_TW2))[t] = make_float2(c,s);
    return;
  } t -= 29040;
  if (t < 14400){ // Tht[h][m]
    int h = t/NH, m = t - h*NH;
    float ang = PI2 * (float)((h*m) % NH) / (float)NH;
    float s,c; sincosf(ang,&s,&c);
    ((float2*)(ws+OFF_THT))[t] = make_float2(c,s);
    return;
  } t -= 14400;
  if (t < 65536){ int i = t>>8, o = t&255; ws[OFF_IWT+t] = iw[o*NC+i]; return; } t -= 65536;
  if (t < 131072){ int i = t>>9, o = t&511; ws[OFF_W1T+t] = w1[o*NC+i]; return; } t -= 131072;
  if (t < 131072){ int i = t>>8, o = t&255; ws[OFF_W2T+t] = w2[o*NHID+i]; return; }
}

// ---------------- instance-norm stats on x -> a0,d0 ----------------
__global__ __launch_bounds__(256) void k_stats0(const float* x, const float* n0w, const float* n0b, float* ws){
  int g = blockIdx.x, c = g & (NC-1);
  const float4* xp = (const float4*)(x + (size_t)g*NHW);
  float s=0.f, q=0.f;
  for(int i=threadIdx.x;i<NHW/4;i+=256){
    float4 v=xp[i];
    s+=v.x+v.y+v.z+v.w;
    q=fmaf(v.x,v.x,fmaf(v.y,v.y,fmaf(v.z,v.z,fmaf(v.w,v.w,q))));
  }
  __shared__ float ls[4], lq[4];
  #pragma unroll
  for(int o=32;o>0;o>>=1){ s+=__shfl_down(s,o,64); q+=__shfl_down(q,o,64); }
  int lane=threadIdx.x&63, wid=threadIdx.x>>6;
  if(!lane){ ls[wid]=s; lq[wid]=q; }
  __syncthreads();
  if(!threadIdx.x){
    s=ls[0]+ls[1]+ls[2]+ls[3]; q=lq[0]+lq[1]+lq[2]+lq[3];
    float m=s*(1.f/NHW), var=q*(1.f/NHW)-m*m;
    float r=rsqrtf(var+REPS);
    float a=r*n0w[c];
    ws[OFF_A0+g]=a; ws[OFF_D0+g]=fmaf(-m,a,n0b[c]);
  }
}

// ---------------- stats on u (=S) -> a1,d1 with FiLM folded ----------------
__global__ __launch_bounds__(256) void k_stats1(const float* gamma, const float* beta,
                                                const float* n1w, const float* n1b, float* ws){
  int g = blockIdx.x, c = g & (NC-1);
  const float4* up = (const float4*)(ws + OFF_S + (size_t)g*NHW);
  float s=0.f, q=0.f;
  for(int i=threadIdx.x;i<NHW/4;i+=256){
    float4 v=up[i];
    s+=v.x+v.y+v.z+v.w;
    q=fmaf(v.x,v.x,fmaf(v.y,v.y,fmaf(v.z,v.z,fmaf(v.w,v.w,q))));
  }
  __shared__ float ls[4], lq[4];
  #pragma unroll
  for(int o=32;o>0;o>>=1){ s+=__shfl_down(s,o,64); q+=__shfl_down(q,o,64); }
  int lane=threadIdx.x&63, wid=threadIdx.x>>6;
  if(!lane){ ls[wid]=s; lq[wid]=q; }
  __syncthreads();
  if(!threadIdx.x){
    s=ls[0]+ls[1]+ls[2]+ls[3]; q=lq[0]+lq[1]+lq[2]+lq[3];
    float m=s*(1.f/NHW), var=q*(1.f/NHW)-m*m;
    float r=rsqrtf(var+REPS);
    float gp1 = 1.f + gamma[c];
    float w = n1w[c];
    ws[OFF_A1+g] = gp1*w*r;
    ws[OFF_D1+g] = gp1*(n1b[c] - m*r*w) + beta[c];
  }
}

// ---------------- forward W real DFT: norm0(x) -> F [b,c,h,k] ----------------
__global__ __launch_bounds__(128) void k_fwdW(const float* x, float* ws){
  int g = blockIdx.y; int h0 = blockIdx.x*8;
  float a = ws[OFF_A0+g], d = ws[OFF_D0+g];
  __shared__ float xr[NW][8];           // [w][r]
  const float* xp = x + (size_t)g*NHW + (size_t)h0*NW;
  for(int idx=threadIdx.x; idx<8*NW; idx+=128){
    int r = idx/NW, w = idx - r*NW;
    xr[w][r] = fmaf(a, xp[idx], d);
  }
  __syncthreads();
  int k = threadIdx.x;
  if(k < NWH){
    float are[8]={}, aim[8]={};
    const float2* T = (const float2*)(ws+OFF_TWT);
    for(int w=0; w<NW; w++){
      float2 cs = T[w*NWH + k];
      float4 x0 = ((const float4*)xr[w])[0];
      float4 x1 = ((const float4*)xr[w])[1];
      #define FWDW(j,v) are[j]=fmaf(v,cs.x,are[j]); aim[j]=fmaf(-(v),cs.y,aim[j]);
      FWDW(0,x0.x) FWDW(1,x0.y) FWDW(2,x0.z) FWDW(3,x0.w)
      FWDW(4,x1.x) FWDW(5,x1.y) FWDW(6,x1.z) FWDW(7,x1.w)
      #undef FWDW
    }
    float* Fre = ws+OFF_FRE; float* Fim = ws+OFF_FIM;
    size_t base = ((size_t)g*NH + h0)*NWH + k;
    #pragma unroll
    for(int r=0;r<8;r++){ Fre[base + (size_t)r*NWH] = are[r]*SC_W; Fim[base + (size_t)r*NWH] = aim[r]*SC_W; }
  }
}

// ---------------- H-direction complex DFT (sg=+1 fwd, -1 inv) ----------------
__global__ __launch_bounds__(128) void k_dftH(float* ws, const float* sre, const float* sim,
                                              float* dre, float* dim_, float sg){
  int g = blockIdx.y, k0 = blockIdx.x*8;
  __shared__ float fr[NH][8], fi[NH][8];
  size_t pb = (size_t)g*NHWF;
  for(int idx=threadIdx.x; idx<NH*8; idx+=128){
    int h = idx>>3, j = idx&7, k = k0+j;
    float vr=0.f, vi=0.f;
    if(k<NWH){ vr=sre[pb+(size_t)h*NWH+k]; vi=sim[pb+(size_t)h*NWH+k]; }
    fr[h][j]=vr; fi[h][j]=vi;
  }
  __syncthreads();
  int m = threadIdx.x;
  if(m < NH){
    float are[8]={}, aim[8]={};
    const float2* T = (const float2*)(ws+OFF_THT);
    for(int h=0;h<NH;h++){
      float2 cs = T[h*NH+m];
      float cx = cs.x, sy = sg*cs.y;
      float4 f0=((const float4*)fr[h])[0], f1=((const float4*)fr[h])[1];
      float4 g0=((const float4*)fi[h])[0], g1=((const float4*)fi[h])[1];
      #define DFTH(j,r,ii) are[j]=fmaf(r,cx,fmaf(ii,sy,are[j])); aim[j]=fmaf(ii,cx,fmaf(-(r),sy,aim[j]));
      DFTH(0,f0.x,g0.x) DFTH(1,f0.y,g0.y) DFTH(2,f0.z,g0.z) DFTH(3,f0.w,g0.w)
      DFTH(4,f1.x,g1.x) DFTH(5,f1.y,g1.y) DFTH(6,f1.z,g1.z) DFTH(7,f1.w,g1.w)
      #undef DFTH
    }
    #pragma unroll
    for(int j=0;j<8;j++){
      int k=k0+j;
      if(k<NWH){ size_t o = pb + (size_t)m*NWH + k; dre[o]=are[j]*SC_H; dim_[o]=aim[j]*SC_H; }
    }
  }
}

// ---------------- complex channel mix: G -> F(Y) ----------------
__global__ __launch_bounds__(256) void k_mix(float* ws, const float* wsr, const float* wsi){
  int b = blockIdx.y; int p0 = blockIdx.x*8;
  __shared__ float gre[NC][8], gim[NC][8];
  const float* Gre = ws+OFF_GRE; const float* Gim = ws+OFF_GIM;
  int t = threadIdx.x;
  {
    size_t base = ((size_t)(b*NC+t))*NHWF + p0;
    ((float4*)gre[t])[0] = ((const float4*)(Gre+base))[0];
    ((float4*)gre[t])[1] = ((const float4*)(Gre+base))[1];
    ((float4*)gim[t])[0] = ((const float4*)(Gim+base))[0];
    ((float4*)gim[t])[1] = ((const float4*)(Gim+base))[1];
  }
  __syncthreads();
  float yre[8]={}, yim[8]={};
  for(int i=0;i<NC;i++){
    float wr = wsr[i*NC+t];
    float wi = wsi[i*NC+t];
    float4 r0=((const float4*)gre[i])[0], r1=((const float4*)gre[i])[1];
    float4 m0=((const float4*)gim[i])[0], m1=((const float4*)gim[i])[1];
    #define CMIX(j,rr,mm) yre[j]=fmaf(rr,wr,fmaf(-(mm),wi,yre[j])); yim[j]=fmaf(rr,wi,fmaf(mm,wr,yim[j]));
    CMIX(0,r0.x,m0.x) CMIX(1,r0.y,m0.y) CMIX(2,r0.z,m0.z) CMIX(3,r0.w,m0.w)
    CMIX(4,r1.x,m1.x) CMIX(5,r1.y,m1.y) CMIX(6,r1.z,m1.z) CMIX(7,r1.w,m1.w)
    #undef CMIX
  }
  float* Yre = ws+OFF_FRE; float* Yim = ws+OFF_FIM;
  size_t ob = ((size_t)(b*NC+t))*NHWF + p0;
  ((float4*)(Yre+ob))[0] = make_float4(yre[0],yre[1],yre[2],yre[3]);
  ((float4*)(Yre+ob))[1] = make_float4(yre[4],yre[5],yre[6],yre[7]);
  ((float4*)(Yim+ob))[0] = make_float4(yim[0],yim[1],yim[2],yim[3]);
  ((float4*)(Yim+ob))[1] = make_float4(yim[4],yim[5],yim[6],yim[7]);
}

// ---------------- inverse W real DFT: G(Z) -> S ----------------
__global__ __launch_bounds__(256) void k_invW(float* ws){
  int g = blockIdx.y; int h0 = blockIdx.x*8;
  __shared__ float zr[NWH][8], zi[NWH][8];   // [k][r]
  const float* Zre = ws+OFF_GRE; const float* Zim = ws+OFF_GIM;
  size_t pb = ((size_t)g*NH + h0)*NWH;
  for(int idx=threadIdx.x; idx<8*NWH; idx+=256){
    int r = idx/NWH, k = idx - r*NWH;
    zr[k][r] = Zre[pb + (size_t)r*NWH + k];
    zi[k][r] = Zim[pb + (size_t)r*NWH + k];
  }
  __syncthreads();
  int w = threadIdx.x;
  if(w < NW){
    float acc[8];
    float sgn = (w&1)? -1.f : 1.f;
    {
      float4 a0=((const float4*)zr[0])[0], a1=((const float4*)zr[0])[1];
      float4 n0=((const float4*)zr[120])[0], n1=((const float4*)zr[120])[1];
      acc[0]=fmaf(sgn,n0.x,a0.x); acc[1]=fmaf(sgn,n0.y,a0.y); acc[2]=fmaf(sgn,n0.z,a0.z); acc[3]=fmaf(sgn,n0.w,a0.w);
      acc[4]=fmaf(sgn,n1.x,a1.x); acc[5]=fmaf(sgn,n1.y,a1.y); acc[6]=fmaf(sgn,n1.z,a1.z); acc[7]=fmaf(sgn,n1.w,a1.w);
    }
    const float2* T = (const float2*)(ws+OFF_TW2);
    for(int k=1;k<120;k++){
      float2 cs = T[k*NW + w];
      float c2 = 2.f*cs.x, s2 = 2.f*cs.y;
      float4 r0=((const float4*)zr[k])[0], r1=((const float4*)zr[k])[1];
      float4 m0=((const float4*)zi[k])[0], m1=((const float4*)zi[k])[1];
      #define IW(j,rr,mm) acc[j]=fmaf(rr,c2,fmaf(-(mm),s2,acc[j]));
      IW(0,r0.x,m0.x) IW(1,r0.y,m0.y) IW(2,r0.z,m0.z) IW(3,r0.w,m0.w)
      IW(4,r1.x,m1.x) IW(5,r1.y,m1.y) IW(6,r1.z,m1.z) IW(7,r1.w,m1.w)
      #undef IW
    }
    float* S = ws+OFF_S;
    size_t ob = ((size_t)g*NH + h0)*NW + w;
    #pragma unroll
    for(int r=0;r<8;r++) S[ob + (size_t)r*NW] = acc[r]*SC_W;
  }
}

// ---------------- inner skip conv + GELU, in-place on S ----------------
__global__ __launch_bounds__(256) void k_inner(const float* x, const float* ib, float* ws){
  int b = blockIdx.y; int p0 = blockIdx.x*16;
  __shared__ float xs[NC][16];
  int t = threadIdx.x;
  const float* xp = x + ((size_t)(b*NC+t))*NHW + p0;
  ((float4*)xs[t])[0] = ((const float4*)xp)[0];
  ((float4*)xs[t])[1] = ((const float4*)xp)[1];
  ((float4*)xs[t])[2] = ((const float4*)xp)[2];
  ((float4*)xs[t])[3] = ((const float4*)xp)[3];
  __syncthreads();
  float acc[16]={};
  const float* iwT = ws+OFF_IWT;
  for(int i=0;i<NC;i++){
    float wv = iwT[i*NC+t];
    float4 a0=((const float4*)xs[i])[0], a1=((const float4*)xs[i])[1];
    float4 a2=((const float4*)xs[i])[2], a3=((const float4*)xs[i])[3];
    #define FMA4(v,o) acc[o]=fmaf(v.x,wv,acc[o]); acc[o+1]=fmaf(v.y,wv,acc[o+1]); acc[o+2]=fmaf(v.z,wv,acc[o+2]); acc[o+3]=fmaf(v.w,wv,acc[o+3]);
    FMA4(a0,0) FMA4(a1,4) FMA4(a2,8) FMA4(a3,12)
    #undef FMA4
  }
  float bb = ib[t];
  float* S = ws+OFF_S;
  size_t ob = ((size_t)(b*NC+t))*NHW + p0;
  #pragma unroll
  for(int j=0;j<16;j++){ S[ob+j] = gelu_f(S[ob+j] + acc[j] + bb); }
}

// ---------------- MLP layer 1 (256->512) + GELU -> Hd (bf16) ----------------
__global__ __launch_bounds__(512) void k_mlp1(const float* b1, float* ws){
  int b = blockIdx.y; int p0 = blockIdx.x*16;
  __shared__ float us[NC][16];
  int t = threadIdx.x;   // 512
  const float* S = ws+OFF_S;
  {
    int i = t>>1, j0 = (t&1)*8;
    float a = ws[OFF_A1 + b*NC + i], d = ws[OFF_D1 + b*NC + i];
    const float* sp = S + ((size_t)(b*NC+i))*NHW + p0 + j0;
    #pragma unroll
    for(int e=0;e<8;e++) us[i][j0+e] = fmaf(a, sp[e], d);
  }
  __syncthreads();
  float acc[16]={};
  const float* w1T = ws+OFF_W1T;
  for(int i=0;i<NC;i++){
    float wv = w1T[i*NHID+t];
    float4 a0=((const float4*)us[i])[0], a1=((const float4*)us[i])[1];
    float4 a2=((const float4*)us[i])[2], a3=((const float4*)us[i])[3];
    #define FMA4(v,o) acc[o]=fmaf(v.x,wv,acc[o]); acc[o+1]=fmaf(v.y,wv,acc[o+1]); acc[o+2]=fmaf(v.z,wv,acc[o+2]); acc[o+3]=fmaf(v.w,wv,acc[o+3]);
    FMA4(a0,0) FMA4(a1,4) FMA4(a2,8) FMA4(a3,12)
    #undef FMA4
  }
  float bb = b1[t];
  bf16* Hd = (bf16*)(ws+OFF_HD);
  size_t ob = ((size_t)(b*NHID+t))*NHW + p0;
  #pragma unroll
  for(int j=0;j<16;j++) Hd[ob+j] = __float2bfloat16(gelu_f(acc[j] + bb));
}

// ---------------- MLP layer 2 (512->256) + residual -> out (fp32) ----------------
__global__ __launch_bounds__(256) void k_mlp2(const float* x, const float* b2, float* ws, float* out){
  int b = blockIdx.y; int p0 = blockIdx.x*16;
  __shared__ float hs[NHID][16];   // 32 KB
  int t = threadIdx.x;   // 256
  const bf16* Hd = (const bf16*)(ws+OFF_HD);
  {
    #pragma unroll
    for(int rr=0;rr<2;rr++){
      int i = t*2 + rr;
      const bf16* hp = Hd + ((size_t)(b*NHID+i))*NHW + p0;
      #pragma unroll
      for(int j=0;j<16;j++) hs[i][j] = b2f(hp[j]);
    }
  }
  __syncthreads();
  float acc[16]={};
  const float* w2T = ws+OFF_W2T;
  for(int i=0;i<NHID;i++){
    float wv = w2T[i*NC+t];
    float4 a0=((const float4*)hs[i])[0], a1=((const float4*)hs[i])[1];
    float4 a2=((const float4*)hs[i])[2], a3=((const float4*)hs[i])[3];
    #define FMA4(v,o) acc[o]=fmaf(v.x,wv,acc[o]); acc[o+1]=fmaf(v.y,wv,acc[o+1]); acc[o+2]=fmaf(v.z,wv,acc[o+2]); acc[o+3]=fmaf(v.w,wv,acc[o+3]);
    FMA4(a0,0) FMA4(a1,4) FMA4(a2,8) FMA4(a3,12)
    #undef FMA4
  }
  float bb = b2[t];
  const float* xp = x + ((size_t)(b*NC+t))*NHW + p0;
  float* op = out + ((size_t)(b*NC+t))*NHW + p0;
  #pragma unroll
  for(int j=0;j<16;j++) op[j] = acc[j] + bb + xp[j];
}

extern "C" void kernel_launch(void* const* d_in, const int* in_sizes, int n_in,
                              void* d_out, int out_size, void* d_ws, size_t ws_size,
                              hipStream_t stream) {
  const float* x     = (const float*)d_in[0];
  const float* gamma = (const float*)d_in[1];
  const float* beta  = (const float*)d_in[2];
  const float* n0w   = (const float*)d_in[3];
  const float* n0b   = (const float*)d_in[4];
  const float* n1w   = (const float*)d_in[5];
  const float* n1b   = (const float*)d_in[6];
  const float* wsr   = (const float*)d_in[7];
  const float* wsi   = (const float*)d_in[8];
  const float* iw    = (const float*)d_in[9];
  const float* ib    = (const float*)d_in[10];
  const float* w1    = (const float*)d_in[11];
  const float* b1    = (const float*)d_in[12];
  const float* w2    = (const float*)d_in[13];
  const float* b2    = (const float*)d_in[14];
  float* ws = (float*)d_ws;
  float* out = (float*)d_out;

  if (ws_size < WS_FLOATS_NEEDED*4ULL) return;   // workspace too small -> loud failure

  k_setup <<<dim3(1564),       dim3(256), 0, stream>>>(ws, iw, w1, w2);
  k_stats0<<<dim3(512),        dim3(256), 0, stream>>>(x, n0w, n0b, ws);
  k_fwdW  <<<dim3(15,512),     dim3(128), 0, stream>>>(x, ws);
  k_dftH  <<<dim3(16,512),     dim3(128), 0, stream>>>(ws, ws+OFF_FRE, ws+OFF_FIM, ws+OFF_GRE, ws+OFF_GIM,  1.f);
  k_mix   <<<dim3(1815,NB),    dim3(256), 0, stream>>>(ws, wsr, wsi);
  k_dftH  <<<dim3(16,512),     dim3(128), 0, stream>>>(ws, ws+OFF_FRE, ws+OFF_FIM, ws+OFF_GRE, ws+OFF_GIM, -1.f);
  k_invW  <<<dim3(15,512),     dim3(256), 0, stream>>>(ws);
  k_inner <<<dim3(1800,NB),    dim3(256), 0, stream>>>(x, ib, ws);
  k_stats1<<<dim3(512),        dim3(256), 0, stream>>>(gamma, beta, n1w, n1b, ws);
  k_mlp1  <<<dim3(1800,NB),    dim3(512), 0, stream>>>(b1, ws);
  k_mlp2  <<<dim3(1800,NB),    dim3(256), 0, stream>>>(x, b2, ws, out);
}

// Round 3
// 1037.836 us; speedup vs baseline: 1.7709x; 1.7709x over previous
//
#include <hip/hip_runtime.h>
#include <hip/hip_bf16.h>

typedef __hip_bfloat16 bf16;
typedef short short8 __attribute__((ext_vector_type(8)));
typedef float f32x4 __attribute__((ext_vector_type(4)));

#define NB 2
#define NC 256
#define NH 120
#define NW 240
#define NWH 121
#define NKP 128          // padded k-stride for spectral arrays
#define NSP (NH*NKP)     // 15360 spectral "pixels" (padded)
#define NHW (NH*NW)      // 28800
#define NHID 512
#define REPS 1e-5f
#define SC_W 0.06454972243679028f   // 1/sqrt(240)
#define SC_H 0.09128709291752769f   // 1/sqrt(120)

__device__ __forceinline__ float gelu_f(float x){ return 0.5f*x*(1.f+erff(x*0.7071067811865476f)); }
__device__ __forceinline__ float us2f(ushort u){ union{float f; uint v;} c; c.v=((uint)u)<<16; return c.f; }
__device__ __forceinline__ ushort f2us(float f){ bf16 b=__float2bfloat16(f); return *(ushort*)&b; }

// ---- workspace float offsets ----
#define OFF_A0  0
#define OFF_D0  512
#define OFF_A1  1024
#define OFF_D1  1536
#define OFF_TWT 2048        // float2[240][121]
#define OFF_THT 60128       // float2[120][120]
#define OFF_TW2 88928       // float2[121][240]
#define OFF_WRT 147008      // bf16[256][256] = w_spec_r^T  [o][i]
#define OFF_WIT 179776      // bf16[256][256] = w_spec_i^T
#define OFF_IWB 212544      // bf16[256][256] inner_w [o][i]
#define OFF_W1B 245312      // bf16[512][256]
#define OFF_W2B 310848      // bf16[256][512]
#define OFF_FRE 376384      // bf16[2*256][15360]
#define OFF_FIM 4308544
#define OFF_GRE 8240704
#define OFF_GIM 12172864
#define OFF_GTR 16105024    // bf16[2][15360][256]  G transposed (re)
#define OFF_GTI 20037184
#define OFF_U   23969344    // float[2*256][28800]
#define OFF_H   38714944    // bf16[2*512][28800]
#define OFF_XT  OFF_FRE     // bf16[2][28800][256]  (aliases F; F dead by then)
#define OFF_UT  OFF_GTR     // bf16[2][28800][256]  (aliases GT)
#define OFF_HT  OFF_U       // bf16[2][28800][512]  (aliases U)
#define WS_FLOATS 53460544ULL

// ---------------- setup: twiddles fp32 + weights bf16 ----------------
__global__ __launch_bounds__(256) void k_setup(float* ws, const float* wsr, const float* wsi,
                                               const float* iw, const float* w1, const float* w2){
  int t = blockIdx.x*256 + threadIdx.x;
  const float PI2 = 6.283185307179586f;
  if (t < 29040){ int w=t/NWH,k=t-w*NWH; float s,c; sincosf(PI2*(float)((w*k)%NW)/(float)NW,&s,&c);
    ((float2*)(ws+OFF_TWT))[t]=make_float2(c,s); return; } t-=29040;
  if (t < 14400){ int h=t/NH,m=t-h*NH; float s,c; sincosf(PI2*(float)((h*m)%NH)/(float)NH,&s,&c);
    ((float2*)(ws+OFF_THT))[t]=make_float2(c,s); return; } t-=14400;
  if (t < 29040){ int k=t/NW,w=t-k*NW; float s,c; sincosf(PI2*(float)((w*k)%NW)/(float)NW,&s,&c);
    ((float2*)(ws+OFF_TW2))[t]=make_float2(c,s); return; } t-=29040;
  if (t < 65536){ int o=t>>8,i=t&255; ((ushort*)(ws+OFF_WRT))[t]=f2us(wsr[i*NC+o]); return; } t-=65536;
  if (t < 65536){ int o=t>>8,i=t&255; ((ushort*)(ws+OFF_WIT))[t]=f2us(wsi[i*NC+o]); return; } t-=65536;
  if (t < 65536){ ((ushort*)(ws+OFF_IWB))[t]=f2us(iw[t]); return; } t-=65536;
  if (t < 131072){ ((ushort*)(ws+OFF_W1B))[t]=f2us(w1[t]); return; } t-=131072;
  if (t < 131072){ ((ushort*)(ws+OFF_W2B))[t]=f2us(w2[t]); return; }
}

// ---------------- instance-norm stats ----------------
__global__ __launch_bounds__(256) void k_stats0(const float* x, const float* n0w, const float* n0b, float* ws){
  int g = blockIdx.x, c = g & (NC-1);
  const float4* xp = (const float4*)(x + (size_t)g*NHW);
  float s=0.f, q=0.f;
  for(int i=threadIdx.x;i<NHW/4;i+=256){
    float4 v=xp[i];
    s+=v.x+v.y+v.z+v.w;
    q=fmaf(v.x,v.x,fmaf(v.y,v.y,fmaf(v.z,v.z,fmaf(v.w,v.w,q))));
  }
  __shared__ float ls[4], lq[4];
  #pragma unroll
  for(int o=32;o>0;o>>=1){ s+=__shfl_down(s,o,64); q+=__shfl_down(q,o,64); }
  int lane=threadIdx.x&63, wid=threadIdx.x>>6;
  if(!lane){ ls[wid]=s; lq[wid]=q; }
  __syncthreads();
  if(!threadIdx.x){
    s=ls[0]+ls[1]+ls[2]+ls[3]; q=lq[0]+lq[1]+lq[2]+lq[3];
    float m=s*(1.f/NHW), var=q*(1.f/NHW)-m*m;
    float r=rsqrtf(var+REPS);
    float a=r*n0w[c];
    ws[OFF_A0+g]=a; ws[OFF_D0+g]=fmaf(-m,a,n0b[c]);
  }
}

__global__ __launch_bounds__(256) void k_stats1(const float* gamma, const float* beta,
                                                const float* n1w, const float* n1b, float* ws){
  int g = blockIdx.x, c = g & (NC-1);
  const float4* up = (const float4*)(ws + OFF_U + (size_t)g*NHW);
  float s=0.f, q=0.f;
  for(int i=threadIdx.x;i<NHW/4;i+=256){
    float4 v=up[i];
    s+=v.x+v.y+v.z+v.w;
    q=fmaf(v.x,v.x,fmaf(v.y,v.y,fmaf(v.z,v.z,fmaf(v.w,v.w,q))));
  }
  __shared__ float ls[4], lq[4];
  #pragma unroll
  for(int o=32;o>0;o>>=1){ s+=__shfl_down(s,o,64); q+=__shfl_down(q,o,64); }
  int lane=threadIdx.x&63, wid=threadIdx.x>>6;
  if(!lane){ ls[wid]=s; lq[wid]=q; }
  __syncthreads();
  if(!threadIdx.x){
    s=ls[0]+ls[1]+ls[2]+ls[3]; q=lq[0]+lq[1]+lq[2]+lq[3];
    float m=s*(1.f/NHW), var=q*(1.f/NHW)-m*m;
    float r=rsqrtf(var+REPS);
    float gp1 = 1.f + gamma[c];
    float w = n1w[c];
    ws[OFF_A1+g] = gp1*w*r;
    ws[OFF_D1+g] = gp1*(n1b[c] - m*r*w) + beta[c];
  }
}

// ---------------- forward W real DFT: norm0(x) -> F bf16 [g][h][128] ----------------
__global__ __launch_bounds__(128) void k_fwdW(const float* x, float* ws){
  int g = blockIdx.y; int h0 = blockIdx.x*8;
  float a = ws[OFF_A0+g], d = ws[OFF_D0+g];
  __shared__ float xr[NW][8];
  const float* xp = x + (size_t)g*NHW + (size_t)h0*NW;
  for(int idx=threadIdx.x; idx<8*NW; idx+=128){
    int r = idx/NW, w = idx - r*NW;
    xr[w][r] = fmaf(a, xp[idx], d);
  }
  __syncthreads();
  int k = threadIdx.x;
  if(k < NWH){
    float are[8]={}, aim[8]={};
    const float2* T = (const float2*)(ws+OFF_TWT);
    for(int w=0; w<NW; w++){
      float2 cs = T[w*NWH + k];
      float4 x0 = ((const float4*)xr[w])[0];
      float4 x1 = ((const float4*)xr[w])[1];
      #define FWDW(j,v) are[j]=fmaf(v,cs.x,are[j]); aim[j]=fmaf(-(v),cs.y,aim[j]);
      FWDW(0,x0.x) FWDW(1,x0.y) FWDW(2,x0.z) FWDW(3,x0.w)
      FWDW(4,x1.x) FWDW(5,x1.y) FWDW(6,x1.z) FWDW(7,x1.w)
      #undef FWDW
    }
    ushort* Fre = (ushort*)(ws+OFF_FRE); ushort* Fim = (ushort*)(ws+OFF_FIM);
    size_t base = (size_t)g*NSP + (size_t)h0*NKP + k;
    #pragma unroll
    for(int r=0;r<8;r++){ Fre[base + (size_t)r*NKP] = f2us(are[r]*SC_W); Fim[base + (size_t)r*NKP] = f2us(aim[r]*SC_W); }
  }
}

// ---------------- H-direction complex DFT, bf16 in/out ----------------
__global__ __launch_bounds__(128) void k_dftH(const float* ws, const ushort* sre, const ushort* sim,
                                              ushort* dre, ushort* dim_, float sg){
  int g = blockIdx.y, k0 = blockIdx.x*8;
  __shared__ float fr[NH][8], fi[NH][8];
  size_t pb = (size_t)g*NSP;
  int t = threadIdx.x;
  if(t < NH){
    uint4 ur = *(const uint4*)(sre + pb + (size_t)t*NKP + k0);
    uint4 ui = *(const uint4*)(sim + pb + (size_t)t*NKP + k0);
    const ushort* hr = (const ushort*)&ur; const ushort* hi = (const ushort*)&ui;
    #pragma unroll
    for(int j=0;j<8;j++){ fr[t][j]=us2f(hr[j]); fi[t][j]=us2f(hi[j]); }
  }
  __syncthreads();
  int m = t;
  if(m < NH){
    float are[8]={}, aim[8]={};
    const float2* T = (const float2*)(ws+OFF_THT);
    for(int h=0;h<NH;h++){
      float2 cs = T[h*NH+m];
      float cx = cs.x, sy = sg*cs.y;
      float4 f0=((const float4*)fr[h])[0], f1=((const float4*)fr[h])[1];
      float4 g0=((const float4*)fi[h])[0], g1=((const float4*)fi[h])[1];
      #define DFTH(j,r,ii) are[j]=fmaf(r,cx,fmaf(ii,sy,are[j])); aim[j]=fmaf(ii,cx,fmaf(-(r),sy,aim[j]));
      DFTH(0,f0.x,g0.x) DFTH(1,f0.y,g0.y) DFTH(2,f0.z,g0.z) DFTH(3,f0.w,g0.w)
      DFTH(4,f1.x,g1.x) DFTH(5,f1.y,g1.y) DFTH(6,f1.z,g1.z) DFTH(7,f1.w,g1.w)
      #undef DFTH
    }
    union { ushort s[8]; uint4 u; } pr, pi;
    #pragma unroll
    for(int j=0;j<8;j++){ pr.s[j]=f2us(are[j]*SC_H); pi.s[j]=f2us(aim[j]*SC_H); }
    *(uint4*)(dre + pb + (size_t)m*NKP + k0) = pr.u;
    *(uint4*)(dim_ + pb + (size_t)m*NKP + k0) = pi.u;
  }
}

// ---------------- 64x64 bf16 transpose: [c][p] -> [p][c]  (G arrays) ----------------
__global__ __launch_bounds__(256) void k_tG(const ushort* src, ushort* dst){
  __shared__ ushort lt[64][72];
  int b=blockIdx.z, i0=blockIdx.y*64, p0=blockIdx.x*64;
  int t=threadIdx.x, r=t>>2, q=t&3;
  const ushort* sp = src + (size_t)(b*NC+i0+r)*NSP + p0 + q*16;
  uint4 u0=*(const uint4*)sp, u1=*(const uint4*)(sp+8);
  *(uint4*)&lt[r][q*16]=u0; *(uint4*)&lt[r][q*16+8]=u1;
  __syncthreads();
  int pr=t>>2, q2=t&3;
  union { ushort s[8]; uint4 u; } o0, o1;
  #pragma unroll
  for(int e=0;e<8;e++){ o0.s[e]=lt[q2*16+e][pr]; o1.s[e]=lt[q2*16+8+e][pr]; }
  ushort* dp = dst + (size_t)(b*NSP+p0+pr)*NC + i0 + q2*16;
  *(uint4*)dp = o0.u; *(uint4*)(dp+8) = o1.u;
}

// ---------------- fp32 [c][p] -> bf16 [p][c] transpose (x) ----------------
__global__ __launch_bounds__(256) void k_tX(const float* src, ushort* dst){
  __shared__ ushort lt[64][72];
  int b=blockIdx.z, i0=blockIdx.y*64, p0=blockIdx.x*64;
  int t=threadIdx.x, r=t>>2, q=t&3;
  const float* sp = src + (size_t)(b*NC+i0+r)*NHW + p0 + q*16;
  union { ushort s[8]; uint4 u; } w0, w1;
  #pragma unroll
  for(int e=0;e<8;e++){ w0.s[e]=f2us(sp[e]); w1.s[e]=f2us(sp[8+e]); }
  *(uint4*)&lt[r][q*16]=w0.u; *(uint4*)&lt[r][q*16+8]=w1.u;
  __syncthreads();
  int pr=t>>2, q2=t&3;
  union { ushort s[8]; uint4 u; } o0, o1;
  #pragma unroll
  for(int e=0;e<8;e++){ o0.s[e]=lt[q2*16+e][pr]; o1.s[e]=lt[q2*16+8+e][pr]; }
  ushort* dp = dst + (size_t)(b*NHW+p0+pr)*NC + i0 + q2*16;
  *(uint4*)dp = o0.u; *(uint4*)(dp+8) = o1.u;
}

// ---------------- U fp32 [c][p] + affine -> bf16 [p][c] (mlp1 input) ----------------
__global__ __launch_bounds__(256) void k_tU(const float* ws, ushort* dst){
  __shared__ ushort lt[64][72];
  int b=blockIdx.z, i0=blockIdx.y*64, p0=blockIdx.x*64;
  int t=threadIdx.x, r=t>>2, q=t&3;
  int c = i0 + r;
  float a = ws[OFF_A1 + b*NC + c], d = ws[OFF_D1 + b*NC + c];
  const float* sp = ws + OFF_U + (size_t)(b*NC+c)*NHW + p0 + q*16;
  union { ushort s[8]; uint4 u; } w0, w1;
  #pragma unroll
  for(int e=0;e<8;e++){ w0.s[e]=f2us(fmaf(a,sp[e],d)); w1.s[e]=f2us(fmaf(a,sp[8+e],d)); }
  *(uint4*)&lt[r][q*16]=w0.u; *(uint4*)&lt[r][q*16+8]=w1.u;
  __syncthreads();
  int pr=t>>2, q2=t&3;
  union { ushort s[8]; uint4 u; } o0, o1;
  #pragma unroll
  for(int e=0;e<8;e++){ o0.s[e]=lt[q2*16+e][pr]; o1.s[e]=lt[q2*16+8+e][pr]; }
  ushort* dp = dst + (size_t)(b*NHW+p0+pr)*NC + i0 + q2*16;
  *(uint4*)dp = o0.u; *(uint4*)(dp+8) = o1.u;
}

// ---------------- H bf16 [o][p] -> bf16 [p][o] (mlp2 input) ----------------
__global__ __launch_bounds__(256) void k_tH(const ushort* src, ushort* dst){
  __shared__ ushort lt[64][72];
  int b=blockIdx.z, i0=blockIdx.y*64, p0=blockIdx.x*64;
  int t=threadIdx.x, r=t>>2, q=t&3;
  const ushort* sp = src + (size_t)(b*NHID+i0+r)*NHW + p0 + q*16;
  uint4 u0=*(const uint4*)sp, u1=*(const uint4*)(sp+8);
  *(uint4*)&lt[r][q*16]=u0; *(uint4*)&lt[r][q*16+8]=u1;
  __syncthreads();
  int pr=t>>2, q2=t&3;
  union { ushort s[8]; uint4 u; } o0, o1;
  #pragma unroll
  for(int e=0;e<8;e++){ o0.s[e]=lt[q2*16+e][pr]; o1.s[e]=lt[q2*16+8+e][pr]; }
  ushort* dp = dst + (size_t)(b*NHW+p0+pr)*NHID + i0 + q2*16;
  *(uint4*)dp = o0.u; *(uint4*)(dp+8) = o1.u;
}

// ---------------- MFMA GEMM: D[m][p] = W[m][:]·actT[p][:]  (no LDS) ----------------
// MODE 0: inner conv  -> U[c][p] = gelu(D + ib + U)   (in-place on U=S)
// MODE 1: mlp1        -> H[o][p] = bf16(gelu(D + b1))
// MODE 2: mlp2        -> out[c][p] = D + b2 + x[c][p]
template<int MODE, int K>
__global__ __launch_bounds__(256) void k_gemm(float* ws, const float* x, const float* bias, float* outf){
  int b = blockIdx.z, p0 = blockIdx.x*64, mg = blockIdx.y;
  int tid = threadIdx.x, w = tid>>6, l = tid&63, lq = l>>4, lr = l&15;
  const ushort* W; const ushort* A;
  if (MODE==0){ W=(const ushort*)(ws+OFF_IWB); A=(const ushort*)(ws+OFF_XT)+(size_t)b*NHW*NC; }
  else if (MODE==1){ W=(const ushort*)(ws+OFF_W1B); A=(const ushort*)(ws+OFF_UT)+(size_t)b*NHW*NC; }
  else { W=(const ushort*)(ws+OFF_W2B); A=(const ushort*)(ws+OFF_HT)+(size_t)b*NHW*NHID; }
  const ushort* ar[4]; const ushort* br[4];
  #pragma unroll
  for(int mt=0;mt<4;mt++) ar[mt] = W + (size_t)(mg*256 + w*64 + mt*16 + lr)*K + lq*8;
  #pragma unroll
  for(int nt=0;nt<4;nt++) br[nt] = A + (size_t)(p0 + nt*16 + lr)*K + lq*8;
  f32x4 acc[4][4] = {};
  for(int k=0;k<K;k+=32){
    short8 af[4], bfr[4];
    #pragma unroll
    for(int mt=0;mt<4;mt++) af[mt] = *(const short8*)(ar[mt]+k);
    #pragma unroll
    for(int nt=0;nt<4;nt++) bfr[nt] = *(const short8*)(br[nt]+k);
    #pragma unroll
    for(int mt=0;mt<4;mt++)
      #pragma unroll
      for(int nt=0;nt<4;nt++)
        acc[mt][nt] = __builtin_amdgcn_mfma_f32_16x16x32_bf16(af[mt], bfr[nt], acc[mt][nt], 0,0,0);
  }
  #pragma unroll
  for(int mt=0;mt<4;mt++){
    int mbase = mg*256 + w*64 + mt*16 + lq*4;
    #pragma unroll
    for(int r=0;r<4;r++){
      int m = mbase + r;
      float bv = bias[m];
      #pragma unroll
      for(int nt=0;nt<4;nt++){
        int n = p0 + nt*16 + lr;
        float v = acc[mt][nt][r];
        if (MODE==0){
          size_t ad = ((size_t)(b*NC+m))*NHW + n;
          outf[ad] = gelu_f(v + bv + outf[ad]);
        } else if (MODE==1){
          ((ushort*)outf)[((size_t)(b*NHID+m))*NHW + n] = f2us(gelu_f(v + bv));
        } else {
          size_t ad = ((size_t)(b*NC+m))*NHW + n;
          outf[ad] = v + bv + x[ad];
        }
      }
    }
  }
}

// ---------------- complex spectral mix via MFMA ----------------
__global__ __launch_bounds__(256) void k_mixg(float* ws){
  int b = blockIdx.z, p0 = blockIdx.x*32;
  int tid = threadIdx.x, w = tid>>6, l = tid&63, lq = l>>4, lr = l&15;
  const ushort* Wr = (const ushort*)(ws+OFF_WRT);
  const ushort* Wi = (const ushort*)(ws+OFF_WIT);
  const ushort* Gr = (const ushort*)(ws+OFF_GTR) + (size_t)b*NSP*NC;
  const ushort* Gi = (const ushort*)(ws+OFF_GTI) + (size_t)b*NSP*NC;
  const ushort *wrr[4], *wir[4], *brr[2], *bir[2];
  #pragma unroll
  for(int mt=0;mt<4;mt++){ size_t ro=(size_t)(w*64+mt*16+lr)*NC+lq*8; wrr[mt]=Wr+ro; wir[mt]=Wi+ro; }
  #pragma unroll
  for(int nt=0;nt<2;nt++){ size_t ro=(size_t)(p0+nt*16+lr)*NC+lq*8; brr[nt]=Gr+ro; bir[nt]=Gi+ro; }
  f32x4 aR[4][2]={}, aI[4][2]={};
  for(int k=0;k<256;k+=32){
    short8 fr[4], fi[4], fin[4], gr[2], gi[2];
    #pragma unroll
    for(int mt=0;mt<4;mt++){
      fr[mt]=*(const short8*)(wrr[mt]+k);
      fi[mt]=*(const short8*)(wir[mt]+k);
      union { short8 s; uint u[4]; } nv; nv.s=fi[mt];
      nv.u[0]^=0x80008000u; nv.u[1]^=0x80008000u; nv.u[2]^=0x80008000u; nv.u[3]^=0x80008000u;
      fin[mt]=nv.s;
    }
    #pragma unroll
    for(int nt=0;nt<2;nt++){ gr[nt]=*(const short8*)(brr[nt]+k); gi[nt]=*(const short8*)(bir[nt]+k); }
    #pragma unroll
    for(int mt=0;mt<4;mt++)
      #pragma unroll
      for(int nt=0;nt<2;nt++){
        aR[mt][nt]=__builtin_amdgcn_mfma_f32_16x16x32_bf16(fr[mt], gr[nt], aR[mt][nt],0,0,0);
        aR[mt][nt]=__builtin_amdgcn_mfma_f32_16x16x32_bf16(fin[mt],gi[nt], aR[mt][nt],0,0,0);
        aI[mt][nt]=__builtin_amdgcn_mfma_f32_16x16x32_bf16(fi[mt], gr[nt], aI[mt][nt],0,0,0);
        aI[mt][nt]=__builtin_amdgcn_mfma_f32_16x16x32_bf16(fr[mt], gi[nt], aI[mt][nt],0,0,0);
      }
  }
  ushort* Yre = (ushort*)(ws+OFF_FRE);
  ushort* Yim = (ushort*)(ws+OFF_FIM);
  #pragma unroll
  for(int mt=0;mt<4;mt++){
    #pragma unroll
    for(int r=0;r<4;r++){
      int m = w*64 + mt*16 + lq*4 + r;
      #pragma unroll
      for(int nt=0;nt<2;nt++){
        int n = p0 + nt*16 + lr;
        size_t ad = (size_t)(b*NC+m)*NSP + n;
        Yre[ad] = f2us(aR[mt][nt][r]);
        Yim[ad] = f2us(aI[mt][nt][r]);
      }
    }
  }
}

// ---------------- inverse W real DFT: Z bf16 -> S fp32 (into U) ----------------
__global__ __launch_bounds__(256) void k_invW(float* ws){
  int g = blockIdx.y; int h0 = blockIdx.x*8;
  __shared__ float zr[NWH][8], zi[NWH][8];
  const ushort* Zre = (const ushort*)(ws+OFF_GRE);
  const ushort* Zim = (const ushort*)(ws+OFF_GIM);
  size_t pb = (size_t)g*NSP + (size_t)h0*NKP;
  for(int idx=threadIdx.x; idx<8*NWH; idx+=256){
    int r = idx/NWH, k = idx - r*NWH;
    zr[k][r] = us2f(Zre[pb + (size_t)r*NKP + k]);
    zi[k][r] = us2f(Zim[pb + (size_t)r*NKP + k]);
  }
  __syncthreads();
  int w = threadIdx.x;
  if(w < NW){
    float acc[8];
    float sgn = (w&1)? -1.f : 1.f;
    {
      float4 a0=((const float4*)zr[0])[0], a1=((const float4*)zr[0])[1];
      float4 n0=((const float4*)zr[120])[0], n1=((const float4*)zr[120])[1];
      acc[0]=fmaf(sgn,n0.x,a0.x); acc[1]=fmaf(sgn,n0.y,a0.y); acc[2]=fmaf(sgn,n0.z,a0.z); acc[3]=fmaf(sgn,n0.w,a0.w);
      acc[4]=fmaf(sgn,n1.x,a1.x); acc[5]=fmaf(sgn,n1.y,a1.y); acc[6]=fmaf(sgn,n1.z,a1.z); acc[7]=fmaf(sgn,n1.w,a1.w);
    }
    const float2* T = (const float2*)(ws+OFF_TW2);
    for(int k=1;k<120;k++){
      float2 cs = T[k*NW + w];
      float c2 = 2.f*cs.x, s2 = 2.f*cs.y;
      float4 r0=((const float4*)zr[k])[0], r1=((const float4*)zr[k])[1];
      float4 m0=((const float4*)zi[k])[0], m1=((const float4*)zi[k])[1];
      #define IW(j,rr,mm) acc[j]=fmaf(rr,c2,fmaf(-(mm),s2,acc[j]));
      IW(0,r0.x,m0.x) IW(1,r0.y,m0.y) IW(2,r0.z,m0.z) IW(3,r0.w,m0.w)
      IW(4,r1.x,m1.x) IW(5,r1.y,m1.y) IW(6,r1.z,m1.z) IW(7,r1.w,m1.w)
      #undef IW
    }
    float* S = ws + OFF_U;
    size_t ob = ((size_t)g*NH + h0)*NW + w;
    #pragma unroll
    for(int r=0;r<8;r++) S[ob + (size_t)r*NW] = acc[r]*SC_W;
  }
}

extern "C" void kernel_launch(void* const* d_in, const int* in_sizes, int n_in,
                              void* d_out, int out_size, void* d_ws, size_t ws_size,
                              hipStream_t stream) {
  const float* x     = (const float*)d_in[0];
  const float* gamma = (const float*)d_in[1];
  const float* beta  = (const float*)d_in[2];
  const float* n0w   = (const float*)d_in[3];
  const float* n0b   = (const float*)d_in[4];
  const float* n1w   = (const float*)d_in[5];
  const float* n1b   = (const float*)d_in[6];
  const float* wsr   = (const float*)d_in[7];
  const float* wsi   = (const float*)d_in[8];
  const float* iw    = (const float*)d_in[9];
  const float* ib    = (const float*)d_in[10];
  const float* w1    = (const float*)d_in[11];
  const float* b1    = (const float*)d_in[12];
  const float* w2    = (const float*)d_in[13];
  const float* b2    = (const float*)d_in[14];
  float* ws = (float*)d_ws;
  float* out = (float*)d_out;
  if (ws_size < WS_FLOATS*4ULL) return;

  k_setup <<<dim3(2076), dim3(256), 0, stream>>>(ws, wsr, wsi, iw, w1, w2);
  k_stats0<<<dim3(512),  dim3(256), 0, stream>>>(x, n0w, n0b, ws);
  k_fwdW  <<<dim3(15,512), dim3(128), 0, stream>>>(x, ws);
  k_dftH  <<<dim3(16,512), dim3(128), 0, stream>>>(ws, (const ushort*)(ws+OFF_FRE), (const ushort*)(ws+OFF_FIM),
                                                   (ushort*)(ws+OFF_GRE), (ushort*)(ws+OFF_GIM),  1.f);
  k_tG    <<<dim3(240,4,2), dim3(256), 0, stream>>>((const ushort*)(ws+OFF_GRE), (ushort*)(ws+OFF_GTR));
  k_tG    <<<dim3(240,4,2), dim3(256), 0, stream>>>((const ushort*)(ws+OFF_GIM), (ushort*)(ws+OFF_GTI));
  k_mixg  <<<dim3(480,1,2), dim3(256), 0, stream>>>(ws);
  k_dftH  <<<dim3(16,512), dim3(128), 0, stream>>>(ws, (const ushort*)(ws+OFF_FRE), (const ushort*)(ws+OFF_FIM),
                                                   (ushort*)(ws+OFF_GRE), (ushort*)(ws+OFF_GIM), -1.f);
  k_invW  <<<dim3(15,512), dim3(256), 0, stream>>>(ws);
  k_tX    <<<dim3(450,4,2), dim3(256), 0, stream>>>(x, (ushort*)(ws+OFF_XT));
  k_gemm<0,256><<<dim3(450,1,2), dim3(256), 0, stream>>>(ws, x, ib, ws+OFF_U);
  k_stats1<<<dim3(512),  dim3(256), 0, stream>>>(gamma, beta, n1w, n1b, ws);
  k_tU    <<<dim3(450,4,2), dim3(256), 0, stream>>>(ws, (ushort*)(ws+OFF_UT));
  k_gemm<1,256><<<dim3(450,2,2), dim3(256), 0, stream>>>(ws, x, b1, ws+OFF_H);
  k_tH    <<<dim3(450,8,2), dim3(256), 0, stream>>>((const ushort*)(ws+OFF_H), (ushort*)(ws+OFF_HT));
  k_gemm<2,512><<<dim3(450,1,2), dim3(256), 0, stream>>>(ws, x, b2, out);
}

// Round 4
// 783.462 us; speedup vs baseline: 2.3459x; 1.3247x over previous
//
#include <hip/hip_runtime.h>
#include <hip/hip_bf16.h>

typedef __hip_bfloat16 bf16;
typedef short short8 __attribute__((ext_vector_type(8)));
typedef float f32x4 __attribute__((ext_vector_type(4)));

#define NB 2
#define NC 256
#define NH 120
#define NW 240
#define NHW (NH*NW)      // 28800
#define NSP 16384        // padded spectral pixels per image (128*128)
#define NHID 512
#define REPS 1e-5f
#define SC_W 0.06454972243679028f   // 1/sqrt(240)
#define SC_H 0.09128709291752769f   // 1/sqrt(120)
#define PI2 6.283185307179586f

__device__ __forceinline__ float gelu_f(float x){ return 0.5f*x*(1.f+erff(x*0.7071067811865476f)); }
__device__ __forceinline__ float us2f(ushort u){ union{float f; uint v;} c; c.v=((uint)u)<<16; return c.f; }
__device__ __forceinline__ ushort f2us(float f){ bf16 b=__float2bfloat16(f); return *(ushort*)&b; }

// ---- workspace float offsets ----
#define OFF_A0   0
#define OFF_D0   512
#define OFF_A1c  1024
#define OFF_D1c  1536
#define OFF_TWF  2048       // bf16[256][256] fwd-W DFT  (n<121: cos; 128+k: -sin)*SC_W
#define OFF_THF  34816      // bf16[256][256] fwd-H (n<128: Gre rows; n>=128: Gim rows)
#define OFF_THI  67584      // bf16[256][256] inv-H
#define OFF_TWI  100352     // bf16[256][256] inv-W real
#define OFF_WRT  133120     // bf16[256][256] w_spec_r^T [o][i]
#define OFF_WIT  165888     // bf16[256][256] w_spec_i^T
#define OFF_IWB  198656     // bf16[256][256] inner_w [o][i]
#define OFF_W1B  231424     // bf16[512][256]
#define OFF_W2B  296960     // bf16[256][512]
#define OFF_RA   362496     // 8388608 floats ping A: {A1, Ft, Gt, Z, XT}
#define OFF_RB   8751104    // 8388608 floats ping B: {F, G, Y, Zt, UT}
#define OFF_U    17139712   // float[2*256][28800]; later HT bf16[2][28800][512]
#define OFF_H    31885312   // bf16[2*512][28800]
#define WS_FLOATS 46630912ULL   // 186.5 MB

// plane sub-offsets (floats)
#define RA0 OFF_RA
#define RA1 (OFF_RA+4194304)
#define RB0 OFF_RB
#define RB1 (OFF_RB+4194304)
#define OFF_FRE RB0
#define OFF_FIM (RB0+3932160)

// ---------------- setup: DFT matrices + weight casts (bf16) ----------------
__global__ __launch_bounds__(256) void k_setup(float* ws, const float* wsr, const float* wsi,
                                               const float* iw, const float* w1, const float* w2){
  int t = blockIdx.x*256 + threadIdx.x;
  if (t < 65536){ // TWF [n][w]
    int n=t>>8, w=t&255; float v=0.f;
    if(w<NW){
      if(n<121){ v = cosf(PI2*(float)((n*w)%NW)/(float)NW)*SC_W; }
      else if(n>=128 && n<249){ int k=n-128; v = -sinf(PI2*(float)((k*w)%NW)/(float)NW)*SC_W; }
    }
    ((ushort*)(ws+OFF_TWF))[t]=f2us(v); return;
  } t-=65536;
  if (t < 65536){ // THF [n][j]: Gre = Fre*c + Fim*s ; Gim = Fim*c - Fre*s
    int n=t>>8, j=t&255; float v=0.f;
    int h = j&127; bool im = (j>=128);
    if(h<NH){
      if(n<128){ int m=n; if(m<NH){ float sn,cs; sincosf(PI2*(float)((m*h)%NH)/(float)NH,&sn,&cs);
        v = (im? sn : cs)*SC_H; } }
      else { int m=n-128; if(m<NH){ float sn,cs; sincosf(PI2*(float)((m*h)%NH)/(float)NH,&sn,&cs);
        v = (im? cs : -sn)*SC_H; } }
    }
    ((ushort*)(ws+OFF_THF))[t]=f2us(v); return;
  } t-=65536;
  if (t < 65536){ // THI [n][j]: Zre = Yre*c - Yim*s ; Zim = Yim*c + Yre*s
    int n=t>>8, j=t&255; float v=0.f;
    int m = j&127; bool im = (j>=128);
    if(m<NH){
      if(n<128){ int h=n; if(h<NH){ float sn,cs; sincosf(PI2*(float)((h*m)%NH)/(float)NH,&sn,&cs);
        v = (im? -sn : cs)*SC_H; } }
      else { int h=n-128; if(h<NH){ float sn,cs; sincosf(PI2*(float)((h*m)%NH)/(float)NH,&sn,&cs);
        v = (im? cs : sn)*SC_H; } }
    }
    ((ushort*)(ws+OFF_THI))[t]=f2us(v); return;
  } t-=65536;
  if (t < 65536){ // TWI [w][j]
    int w=t>>8, j=t&255; float v=0.f;
    if(w<NW){
      int k = j&127; bool im = (j>=128);
      if(k<121){
        float ck = (k==0||k==120)? 1.f : 2.f;
        float sn,cs; sincosf(PI2*(float)((w*k)%NW)/(float)NW,&sn,&cs);
        v = ck*(im? -sn : cs)*SC_W;
      }
    }
    ((ushort*)(ws+OFF_TWI))[t]=f2us(v); return;
  } t-=65536;
  if (t < 65536){ int o=t>>8,i=t&255; ((ushort*)(ws+OFF_WRT))[t]=f2us(wsr[i*NC+o]); return; } t-=65536;
  if (t < 65536){ int o=t>>8,i=t&255; ((ushort*)(ws+OFF_WIT))[t]=f2us(wsi[i*NC+o]); return; } t-=65536;
  if (t < 65536){ ((ushort*)(ws+OFF_IWB))[t]=f2us(iw[t]); return; } t-=65536;
  if (t < 131072){ ((ushort*)(ws+OFF_W1B))[t]=f2us(w1[t]); return; } t-=131072;
  if (t < 131072){ ((ushort*)(ws+OFF_W2B))[t]=f2us(w2[t]); return; }
}

// ---------------- instance-norm stats ----------------
__global__ __launch_bounds__(256) void k_stats0(const float* x, const float* n0w, const float* n0b, float* ws){
  int g = blockIdx.x, c = g & (NC-1);
  const float4* xp = (const float4*)(x + (size_t)g*NHW);
  float s=0.f, q=0.f;
  for(int i=threadIdx.x;i<NHW/4;i+=256){
    float4 v=xp[i];
    s+=v.x+v.y+v.z+v.w;
    q=fmaf(v.x,v.x,fmaf(v.y,v.y,fmaf(v.z,v.z,fmaf(v.w,v.w,q))));
  }
  __shared__ float ls[4], lq[4];
  #pragma unroll
  for(int o=32;o>0;o>>=1){ s+=__shfl_down(s,o,64); q+=__shfl_down(q,o,64); }
  int lane=threadIdx.x&63, wid=threadIdx.x>>6;
  if(!lane){ ls[wid]=s; lq[wid]=q; }
  __syncthreads();
  if(!threadIdx.x){
    s=ls[0]+ls[1]+ls[2]+ls[3]; q=lq[0]+lq[1]+lq[2]+lq[3];
    float m=s*(1.f/NHW), var=q*(1.f/NHW)-m*m;
    float r=rsqrtf(var+REPS);
    float a=r*n0w[c];
    ws[OFF_A0+g]=a; ws[OFF_D0+g]=fmaf(-m,a,n0b[c]);
  }
}

__global__ __launch_bounds__(256) void k_stats1(const float* gamma, const float* beta,
                                                const float* n1w, const float* n1b, float* ws){
  int g = blockIdx.x, c = g & (NC-1);
  const float4* up = (const float4*)(ws + OFF_U + (size_t)g*NHW);
  float s=0.f, q=0.f;
  for(int i=threadIdx.x;i<NHW/4;i+=256){
    float4 v=up[i];
    s+=v.x+v.y+v.z+v.w;
    q=fmaf(v.x,v.x,fmaf(v.y,v.y,fmaf(v.z,v.z,fmaf(v.w,v.w,q))));
  }
  __shared__ float ls[4], lq[4];
  #pragma unroll
  for(int o=32;o>0;o>>=1){ s+=__shfl_down(s,o,64); q+=__shfl_down(q,o,64); }
  int lane=threadIdx.x&63, wid=threadIdx.x>>6;
  if(!lane){ ls[wid]=s; lq[wid]=q; }
  __syncthreads();
  if(!threadIdx.x){
    s=ls[0]+ls[1]+ls[2]+ls[3]; q=lq[0]+lq[1]+lq[2]+lq[3];
    float m=s*(1.f/NHW), var=q*(1.f/NHW)-m*m;
    float r=rsqrtf(var+REPS);
    float gp1 = 1.f + gamma[c];
    float w = n1w[c];
    ws[OFF_A1c+g] = gp1*w*r;
    ws[OFF_D1c+g] = gp1*(n1b[c] - m*r*w) + beta[c];
  }
}

// ---------------- norm+cast: x -> A1 bf16 [g][h][256] (w>=240 zero) ----------------
__global__ __launch_bounds__(256) void k_norm(const float* x, float* ws){
  int h = blockIdx.x, g = blockIdx.y, t = threadIdx.x;
  float a = ws[OFF_A0+g], d = ws[OFF_D0+g];
  ushort v = 0;
  if(t < NW) v = f2us(fmaf(a, x[(size_t)g*NHW + (size_t)h*NW + t], d));
  ((ushort*)(ws+RA0))[(size_t)g*30720 + (size_t)h*256 + t] = v;
}

// ---------------- spectral GEMM: D[m][n] = sum_k A[m][k] * B[n][k] ----------------
// SPLIT: A row = [plane0(128) | plane1(128)], row-stride 128 each; else single 256-stride.
// EPI 0: n<128 -> O0[m*128+n] bf16 ; n>=128 -> O1[m*128+n-128]
// EPI 1: g=m>>7,h=m&127; if(h<120 && n<240) Of[g*28800+h*240+n] = v (fp32)
template<int SPLIT, int EPI>
__global__ __launch_bounds__(256) void k_sgemm(const ushort* Ap0, const ushort* Ap1, const ushort* Bm,
                                               ushort* O0, ushort* O1, float* Of){
  int nb = blockIdx.x*64, mb = blockIdx.y*256;
  int tid = threadIdx.x, w = tid>>6, l = tid&63, lq = l>>4, lr = l&15;
  const ushort* ar0[4]; const ushort* ar1[4]; const ushort* br[4];
  #pragma unroll
  for(int mt=0;mt<4;mt++){
    size_t r = mb + w*64 + mt*16 + lr;
    ar0[mt] = Ap0 + r*(SPLIT?128:256) + lq*8;
    ar1[mt] = SPLIT ? (Ap1 + r*128 + lq*8) : ar0[mt];
  }
  #pragma unroll
  for(int nt=0;nt<4;nt++) br[nt] = Bm + (size_t)(nb + nt*16 + lr)*256 + lq*8;
  f32x4 acc[4][4] = {};
  #pragma unroll
  for(int kk=0;kk<8;kk++){
    int k = kk*32;
    short8 af[4], bfr[4];
    #pragma unroll
    for(int mt=0;mt<4;mt++){
      const ushort* p = SPLIT ? ((k<128 ? ar0[mt] : ar1[mt]) + (k&127)) : (ar0[mt] + k);
      af[mt] = *(const short8*)p;
    }
    #pragma unroll
    for(int nt=0;nt<4;nt++) bfr[nt] = *(const short8*)(br[nt]+k);
    #pragma unroll
    for(int mt=0;mt<4;mt++)
      #pragma unroll
      for(int nt=0;nt<4;nt++)
        acc[mt][nt] = __builtin_amdgcn_mfma_f32_16x16x32_bf16(af[mt], bfr[nt], acc[mt][nt], 0,0,0);
  }
  #pragma unroll
  for(int mt=0;mt<4;mt++){
    #pragma unroll
    for(int r=0;r<4;r++){
      int m = mb + w*64 + mt*16 + lq*4 + r;
      #pragma unroll
      for(int nt=0;nt<4;nt++){
        int n = nb + nt*16 + lr;
        float v = acc[mt][nt][r];
        if (EPI==0){
          if(n<128) O0[(size_t)m*128+n] = f2us(v);
          else      O1[(size_t)m*128+n-128] = f2us(v);
        } else {
          int g = m>>7, h = m&127;
          if(h<NH && n<NW) Of[(size_t)g*NHW + (size_t)h*NW + n] = v;
        }
      }
    }
  }
}

// ---------------- 64x64 bf16 transpose within 128-stride planes ----------------
// src [g][row:srows][128] -> dst [g][col:128][128]; rows>=srows read as 0
__global__ __launch_bounds__(256) void k_t64(const ushort* src, ushort* dst, int srows, int sgstr){
  __shared__ ushort lt[64][72];
  int g=blockIdx.z, i0=blockIdx.y*64, p0=blockIdx.x*64;
  int t=threadIdx.x, r=t>>2, q=t&3;
  int row = i0 + r;
  uint4 u0=make_uint4(0,0,0,0), u1=u0;
  if(row < srows){
    const ushort* sp = src + (size_t)g*sgstr + (size_t)row*128 + p0 + q*16;
    u0=*(const uint4*)sp; u1=*(const uint4*)(sp+8);
  }
  *(uint4*)&lt[r][q*16]=u0; *(uint4*)&lt[r][q*16+8]=u1;
  __syncthreads();
  int pr=t>>2, q2=t&3;
  union { ushort s[8]; uint4 u; } o0, o1;
  #pragma unroll
  for(int e=0;e<8;e++){ o0.s[e]=lt[q2*16+e][pr]; o1.s[e]=lt[q2*16+8+e][pr]; }
  ushort* dp = dst + (size_t)g*NSP + (size_t)(p0+pr)*128 + i0 + q2*16;
  *(uint4*)dp = o0.u; *(uint4*)(dp+8) = o1.u;
}

// ---------------- pixel transpose: [b][c:256][P] -> [b][P][c] ----------------
template<int P>
__global__ __launch_bounds__(256) void k_tP(const ushort* src, ushort* dst){
  __shared__ ushort lt[64][72];
  int b=blockIdx.z, i0=blockIdx.y*64, p0=blockIdx.x*64;
  int t=threadIdx.x, r=t>>2, q=t&3;
  const ushort* sp = src + (size_t)(b*NC+i0+r)*P + p0 + q*16;
  uint4 u0=*(const uint4*)sp, u1=*(const uint4*)(sp+8);
  *(uint4*)&lt[r][q*16]=u0; *(uint4*)&lt[r][q*16+8]=u1;
  __syncthreads();
  int pr=t>>2, q2=t&3;
  union { ushort s[8]; uint4 u; } o0, o1;
  #pragma unroll
  for(int e=0;e<8;e++){ o0.s[e]=lt[q2*16+e][pr]; o1.s[e]=lt[q2*16+8+e][pr]; }
  ushort* dp = dst + ((size_t)b*P + p0 + pr)*NC + i0 + q2*16;
  *(uint4*)dp = o0.u; *(uint4*)(dp+8) = o1.u;
}

// ---------------- fp32 [c][p] -> bf16 [p][c] (x for inner conv) ----------------
__global__ __launch_bounds__(256) void k_tX(const float* src, ushort* dst){
  __shared__ ushort lt[64][72];
  int b=blockIdx.z, i0=blockIdx.y*64, p0=blockIdx.x*64;
  int t=threadIdx.x, r=t>>2, q=t&3;
  const float* sp = src + (size_t)(b*NC+i0+r)*NHW + p0 + q*16;
  union { ushort s[8]; uint4 u; } w0, w1;
  #pragma unroll
  for(int e=0;e<8;e++){ w0.s[e]=f2us(sp[e]); w1.s[e]=f2us(sp[8+e]); }
  *(uint4*)&lt[r][q*16]=w0.u; *(uint4*)&lt[r][q*16+8]=w1.u;
  __syncthreads();
  int pr=t>>2, q2=t&3;
  union { ushort s[8]; uint4 u; } o0, o1;
  #pragma unroll
  for(int e=0;e<8;e++){ o0.s[e]=lt[q2*16+e][pr]; o1.s[e]=lt[q2*16+8+e][pr]; }
  ushort* dp = dst + (size_t)(b*NHW+p0+pr)*NC + i0 + q2*16;
  *(uint4*)dp = o0.u; *(uint4*)(dp+8) = o1.u;
}

// ---------------- U fp32 [c][p] + affine -> bf16 [p][c] ----------------
__global__ __launch_bounds__(256) void k_tU(const float* ws, ushort* dst){
  __shared__ ushort lt[64][72];
  int b=blockIdx.z, i0=blockIdx.y*64, p0=blockIdx.x*64;
  int t=threadIdx.x, r=t>>2, q=t&3;
  int c = i0 + r;
  float a = ws[OFF_A1c + b*NC + c], d = ws[OFF_D1c + b*NC + c];
  const float* sp = ws + OFF_U + (size_t)(b*NC+c)*NHW + p0 + q*16;
  union { ushort s[8]; uint4 u; } w0, w1;
  #pragma unroll
  for(int e=0;e<8;e++){ w0.s[e]=f2us(fmaf(a,sp[e],d)); w1.s[e]=f2us(fmaf(a,sp[8+e],d)); }
  *(uint4*)&lt[r][q*16]=w0.u; *(uint4*)&lt[r][q*16+8]=w1.u;
  __syncthreads();
  int pr=t>>2, q2=t&3;
  union { ushort s[8]; uint4 u; } o0, o1;
  #pragma unroll
  for(int e=0;e<8;e++){ o0.s[e]=lt[q2*16+e][pr]; o1.s[e]=lt[q2*16+8+e][pr]; }
  ushort* dp = dst + (size_t)(b*NHW+p0+pr)*NC + i0 + q2*16;
  *(uint4*)dp = o0.u; *(uint4*)(dp+8) = o1.u;
}

// ---------------- H bf16 [o][p] -> bf16 [p][o] ----------------
__global__ __launch_bounds__(256) void k_tH(const ushort* src, ushort* dst){
  __shared__ ushort lt[64][72];
  int b=blockIdx.z, i0=blockIdx.y*64, p0=blockIdx.x*64;
  int t=threadIdx.x, r=t>>2, q=t&3;
  const ushort* sp = src + (size_t)(b*NHID+i0+r)*NHW + p0 + q*16;
  uint4 u0=*(const uint4*)sp, u1=*(const uint4*)(sp+8);
  *(uint4*)&lt[r][q*16]=u0; *(uint4*)&lt[r][q*16+8]=u1;
  __syncthreads();
  int pr=t>>2, q2=t&3;
  union { ushort s[8]; uint4 u; } o0, o1;
  #pragma unroll
  for(int e=0;e<8;e++){ o0.s[e]=lt[q2*16+e][pr]; o1.s[e]=lt[q2*16+8+e][pr]; }
  ushort* dp = dst + (size_t)(b*NHW+p0+pr)*NHID + i0 + q2*16;
  *(uint4*)dp = o0.u; *(uint4*)(dp+8) = o1.u;
}

// ---------------- channel GEMMs (inner/mlp1/mlp2), no LDS ----------------
template<int MODE, int K>
__global__ __launch_bounds__(256) void k_gemm(float* ws, const float* x, const float* bias, float* outf){
  int b = blockIdx.z, p0 = blockIdx.x*64, mg = blockIdx.y;
  int tid = threadIdx.x, w = tid>>6, l = tid&63, lq = l>>4, lr = l&15;
  const ushort* W; const ushort* A;
  if (MODE==0){ W=(const ushort*)(ws+OFF_IWB); A=(const ushort*)(ws+RA0)+(size_t)b*NHW*NC; }
  else if (MODE==1){ W=(const ushort*)(ws+OFF_W1B); A=(const ushort*)(ws+RB0)+(size_t)b*NHW*NC; }
  else { W=(const ushort*)(ws+OFF_W2B); A=(const ushort*)(ws+OFF_U)+(size_t)b*NHW*NHID; }
  const ushort* ar[4]; const ushort* br[4];
  #pragma unroll
  for(int mt=0;mt<4;mt++) ar[mt] = W + (size_t)(mg*256 + w*64 + mt*16 + lr)*K + lq*8;
  #pragma unroll
  for(int nt=0;nt<4;nt++) br[nt] = A + (size_t)(p0 + nt*16 + lr)*K + lq*8;
  f32x4 acc[4][4] = {};
  for(int k=0;k<K;k+=32){
    short8 af[4], bfr[4];
    #pragma unroll
    for(int mt=0;mt<4;mt++) af[mt] = *(const short8*)(ar[mt]+k);
    #pragma unroll
    for(int nt=0;nt<4;nt++) bfr[nt] = *(const short8*)(br[nt]+k);
    #pragma unroll
    for(int mt=0;mt<4;mt++)
      #pragma unroll
      for(int nt=0;nt<4;nt++)
        acc[mt][nt] = __builtin_amdgcn_mfma_f32_16x16x32_bf16(af[mt], bfr[nt], acc[mt][nt], 0,0,0);
  }
  #pragma unroll
  for(int mt=0;mt<4;mt++){
    int mbase = mg*256 + w*64 + mt*16 + lq*4;
    #pragma unroll
    for(int r=0;r<4;r++){
      int m = mbase + r;
      float bv = bias[m];
      #pragma unroll
      for(int nt=0;nt<4;nt++){
        int n = p0 + nt*16 + lr;
        float v = acc[mt][nt][r];
        if (MODE==0){
          size_t ad = ((size_t)(b*NC+m))*NHW + n;
          outf[ad] = gelu_f(v + bv + outf[ad]);
        } else if (MODE==1){
          ((ushort*)outf)[((size_t)(b*NHID+m))*NHW + n] = f2us(gelu_f(v + bv));
        } else {
          size_t ad = ((size_t)(b*NC+m))*NHW + n;
          outf[ad] = v + bv + x[ad];
        }
      }
    }
  }
}

// ---------------- complex spectral mix via MFMA ----------------
__global__ __launch_bounds__(256) void k_mixg(float* ws){
  int b = blockIdx.z, p0 = blockIdx.x*32;
  int tid = threadIdx.x, w = tid>>6, l = tid&63, lq = l>>4, lr = l&15;
  const ushort* Wr = (const ushort*)(ws+OFF_WRT);
  const ushort* Wi = (const ushort*)(ws+OFF_WIT);
  const ushort* Gr = (const ushort*)(ws+RA0) + (size_t)b*NSP*NC;
  const ushort* Gi = (const ushort*)(ws+RA1) + (size_t)b*NSP*NC;
  const ushort *wrr[4], *wir[4], *brr[2], *bir[2];
  #pragma unroll
  for(int mt=0;mt<4;mt++){ size_t ro=(size_t)(w*64+mt*16+lr)*NC+lq*8; wrr[mt]=Wr+ro; wir[mt]=Wi+ro; }
  #pragma unroll
  for(int nt=0;nt<2;nt++){ size_t ro=(size_t)(p0+nt*16+lr)*NC+lq*8; brr[nt]=Gr+ro; bir[nt]=Gi+ro; }
  f32x4 aR[4][2]={}, aI[4][2]={};
  for(int k=0;k<256;k+=32){
    short8 fr[4], fi[4], fin[4], gr[2], gi[2];
    #pragma unroll
    for(int mt=0;mt<4;mt++){
      fr[mt]=*(const short8*)(wrr[mt]+k);
      fi[mt]=*(const short8*)(wir[mt]+k);
      union { short8 s; uint u[4]; } nv; nv.s=fi[mt];
      nv.u[0]^=0x80008000u; nv.u[1]^=0x80008000u; nv.u[2]^=0x80008000u; nv.u[3]^=0x80008000u;
      fin[mt]=nv.s;
    }
    #pragma unroll
    for(int nt=0;nt<2;nt++){ gr[nt]=*(const short8*)(brr[nt]+k); gi[nt]=*(const short8*)(bir[nt]+k); }
    #pragma unroll
    for(int mt=0;mt<4;mt++)
      #pragma unroll
      for(int nt=0;nt<2;nt++){
        aR[mt][nt]=__builtin_amdgcn_mfma_f32_16x16x32_bf16(fr[mt], gr[nt], aR[mt][nt],0,0,0);
        aR[mt][nt]=__builtin_amdgcn_mfma_f32_16x16x32_bf16(fin[mt],gi[nt], aR[mt][nt],0,0,0);
        aI[mt][nt]=__builtin_amdgcn_mfma_f32_16x16x32_bf16(fi[mt], gr[nt], aI[mt][nt],0,0,0);
        aI[mt][nt]=__builtin_amdgcn_mfma_f32_16x16x32_bf16(fr[mt], gi[nt], aI[mt][nt],0,0,0);
      }
  }
  ushort* Yre = (ushort*)(ws+RB0);
  ushort* Yim = (ushort*)(ws+RB1);
  #pragma unroll
  for(int mt=0;mt<4;mt++){
    #pragma unroll
    for(int r=0;r<4;r++){
      int m = w*64 + mt*16 + lq*4 + r;
      #pragma unroll
      for(int nt=0;nt<2;nt++){
        int n = p0 + nt*16 + lr;
        size_t ad = (size_t)(b*NC+m)*NSP + n;
        Yre[ad] = f2us(aR[mt][nt][r]);
        Yim[ad] = f2us(aI[mt][nt][r]);
      }
    }
  }
}

extern "C" void kernel_launch(void* const* d_in, const int* in_sizes, int n_in,
                              void* d_out, int out_size, void* d_ws, size_t ws_size,
                              hipStream_t stream) {
  const float* x     = (const float*)d_in[0];
  const float* gamma = (const float*)d_in[1];
  const float* beta  = (const float*)d_in[2];
  const float* n0w   = (const float*)d_in[3];
  const float* n0b   = (const float*)d_in[4];
  const float* n1w   = (const float*)d_in[5];
  const float* n1b   = (const float*)d_in[6];
  const float* wsr   = (const float*)d_in[7];
  const float* wsi   = (const float*)d_in[8];
  const float* iw    = (const float*)d_in[9];
  const float* ib    = (const float*)d_in[10];
  const float* w1    = (const float*)d_in[11];
  const float* b1    = (const float*)d_in[12];
  const float* w2    = (const float*)d_in[13];
  const float* b2    = (const float*)d_in[14];
  float* ws = (float*)d_ws;
  float* out = (float*)d_out;
  if (ws_size < WS_FLOATS*4ULL) return;

  k_setup <<<dim3(2816), dim3(256), 0, stream>>>(ws, wsr, wsi, iw, w1, w2);
  k_stats0<<<dim3(512),  dim3(256), 0, stream>>>(x, n0w, n0b, ws);
  k_norm  <<<dim3(120,512), dim3(256), 0, stream>>>(x, ws);
  // GEMM1: A1(RA) -> F(RB planes)
  k_sgemm<0,0><<<dim3(4,240), dim3(256), 0, stream>>>((const ushort*)(ws+RA0), (const ushort*)(ws+RA0),
      (const ushort*)(ws+OFF_TWF), (ushort*)(ws+OFF_FRE), (ushort*)(ws+OFF_FIM), nullptr);
  // T1: F(RB) -> Ft(RA)
  k_t64 <<<dim3(2,2,512), dim3(256), 0, stream>>>((const ushort*)(ws+OFF_FRE), (ushort*)(ws+RA0), NH, NH*128);
  k_t64 <<<dim3(2,2,512), dim3(256), 0, stream>>>((const ushort*)(ws+OFF_FIM), (ushort*)(ws+RA1), NH, NH*128);
  // GEMM2: Ft(RA) -> G(RB)
  k_sgemm<1,0><<<dim3(4,256), dim3(256), 0, stream>>>((const ushort*)(ws+RA0), (const ushort*)(ws+RA1),
      (const ushort*)(ws+OFF_THF), (ushort*)(ws+RB0), (ushort*)(ws+RB1), nullptr);
  // T2: G(RB) -> Gt(RA)  [b][p][c]
  k_tP<NSP><<<dim3(256,4,2), dim3(256), 0, stream>>>((const ushort*)(ws+RB0), (ushort*)(ws+RA0));
  k_tP<NSP><<<dim3(256,4,2), dim3(256), 0, stream>>>((const ushort*)(ws+RB1), (ushort*)(ws+RA1));
  // mix: Gt(RA) -> Y(RB)
  k_mixg <<<dim3(512,1,2), dim3(256), 0, stream>>>(ws);
  // GEMM4: Y(RB) -> Z(RA)
  k_sgemm<1,0><<<dim3(4,256), dim3(256), 0, stream>>>((const ushort*)(ws+RB0), (const ushort*)(ws+RB1),
      (const ushort*)(ws+OFF_THI), (ushort*)(ws+RA0), (ushort*)(ws+RA1), nullptr);
  // T3: Z(RA) -> Zt(RB)
  k_t64 <<<dim3(2,2,512), dim3(256), 0, stream>>>((const ushort*)(ws+RA0), (ushort*)(ws+RB0), 128, NSP);
  k_t64 <<<dim3(2,2,512), dim3(256), 0, stream>>>((const ushort*)(ws+RA1), (ushort*)(ws+RB1), 128, NSP);
  // GEMM5: Zt(RB) -> U (fp32 spatial)
  k_sgemm<1,1><<<dim3(4,256), dim3(256), 0, stream>>>((const ushort*)(ws+RB0), (const ushort*)(ws+RB1),
      (const ushort*)(ws+OFF_TWI), nullptr, nullptr, ws+OFF_U);
  // tail
  k_tX    <<<dim3(450,4,2), dim3(256), 0, stream>>>(x, (ushort*)(ws+RA0));
  k_gemm<0,256><<<dim3(450,1,2), dim3(256), 0, stream>>>(ws, x, ib, ws+OFF_U);
  k_stats1<<<dim3(512),  dim3(256), 0, stream>>>(gamma, beta, n1w, n1b, ws);
  k_tU    <<<dim3(450,4,2), dim3(256), 0, stream>>>(ws, (ushort*)(ws+RB0));
  k_gemm<1,256><<<dim3(450,2,2), dim3(256), 0, stream>>>(ws, x, b1, ws+OFF_H);
  k_tH    <<<dim3(450,8,2), dim3(256), 0, stream>>>((const ushort*)(ws+OFF_H), (ushort*)(ws+OFF_U));
  k_gemm<2,512><<<dim3(450,1,2), dim3(256), 0, stream>>>(ws, x, b2, out);
}

// Round 5
// 649.468 us; speedup vs baseline: 2.8298x; 1.2063x over previous
//
#include <hip/hip_runtime.h>
#include <hip/hip_bf16.h>

typedef __hip_bfloat16 bf16;
typedef short short8 __attribute__((ext_vector_type(8)));
typedef float f32x4 __attribute__((ext_vector_type(4)));

#define NB 2
#define NC 256
#define NH 120
#define NW 240
#define NHW (NH*NW)      // 28800
#define NSP 16384        // padded spectral pixels per image (128*128)
#define NHID 512
#define NPT 450          // pixel tiles of 64
#define REPS 1e-5f
#define SC_W 0.06454972243679028f   // 1/sqrt(240)
#define SC_H 0.09128709291752769f   // 1/sqrt(120)
#define PI2 6.283185307179586f

__device__ __forceinline__ float gelu_f(float x){ return 0.5f*x*(1.f+erff(x*0.7071067811865476f)); }
__device__ __forceinline__ float us2f(ushort u){ union{float f; uint v;} c; c.v=((uint)u)<<16; return c.f; }
__device__ __forceinline__ ushort f2us(float f){ bf16 b=__float2bfloat16(f); return *(ushort*)&b; }

// ---- workspace float offsets ----
#define OFF_A0   0
#define OFF_D0   512
#define OFF_A1c  1024
#define OFF_D1c  1536
#define OFF_TWF  2048       // bf16[256][256] fwd-W DFT
#define OFF_THF  34816      // bf16[256][256] fwd-H
#define OFF_THI  67584      // bf16[256][256] inv-H
#define OFF_TWI  100352     // bf16[256][256] inv-W real
#define OFF_WRT  133120     // bf16[256][256] w_spec_r^T [o][i]
#define OFF_WIT  165888     // bf16[256][256] w_spec_i^T
#define OFF_IWB  198656     // bf16[256][256] inner_w [o][i]
#define OFF_W2B  231424     // bf16[256][512]
#define OFF_W1P  296960     // bf16[2][512][256]  a1-folded mlp_w1
#define OFF_B1P  428032     // f32[2][512]        folded bias1
#define OFF_PS   429056     // f32[2][450][512]   stats partials (sum | sumsq)
#define OFF_RA   889856     // 8388608 floats ping A
#define OFF_RB   9278464    // 8388608 floats ping B
#define WS_FLOATS 17667072ULL   // 70.7 MB

#define RA0 OFF_RA
#define RA1 (OFF_RA+4194304)
#define RB0 OFF_RB
#define RB1 (OFF_RB+4194304)
#define OFF_FRE RB0
#define OFF_FIM (RB0+3932160)

// ---------------- setup: DFT matrices + weight casts ----------------
__global__ __launch_bounds__(256) void k_setup(float* ws, const float* wsr, const float* wsi,
                                               const float* iw, const float* w2){
  int t = blockIdx.x*256 + threadIdx.x;
  if (t < 65536){ // TWF [n][w]
    int n=t>>8, w=t&255; float v=0.f;
    if(w<NW){
      if(n<121){ v = cosf(PI2*(float)((n*w)%NW)/(float)NW)*SC_W; }
      else if(n>=128 && n<249){ int k=n-128; v = -sinf(PI2*(float)((k*w)%NW)/(float)NW)*SC_W; }
    }
    ((ushort*)(ws+OFF_TWF))[t]=f2us(v); return;
  } t-=65536;
  if (t < 65536){ // THF
    int n=t>>8, j=t&255; float v=0.f;
    int h = j&127; bool im = (j>=128);
    if(h<NH){
      if(n<128){ int m=n; if(m<NH){ float sn,cs; sincosf(PI2*(float)((m*h)%NH)/(float)NH,&sn,&cs);
        v = (im? sn : cs)*SC_H; } }
      else { int m=n-128; if(m<NH){ float sn,cs; sincosf(PI2*(float)((m*h)%NH)/(float)NH,&sn,&cs);
        v = (im? cs : -sn)*SC_H; } }
    }
    ((ushort*)(ws+OFF_THF))[t]=f2us(v); return;
  } t-=65536;
  if (t < 65536){ // THI
    int n=t>>8, j=t&255; float v=0.f;
    int m = j&127; bool im = (j>=128);
    if(m<NH){
      if(n<128){ int h=n; if(h<NH){ float sn,cs; sincosf(PI2*(float)((h*m)%NH)/(float)NH,&sn,&cs);
        v = (im? -sn : cs)*SC_H; } }
      else { int h=n-128; if(h<NH){ float sn,cs; sincosf(PI2*(float)((h*m)%NH)/(float)NH,&sn,&cs);
        v = (im? cs : sn)*SC_H; } }
    }
    ((ushort*)(ws+OFF_THI))[t]=f2us(v); return;
  } t-=65536;
  if (t < 65536){ // TWI
    int w=t>>8, j=t&255; float v=0.f;
    if(w<NW){
      int k = j&127; bool im = (j>=128);
      if(k<121){
        float ck = (k==0||k==120)? 1.f : 2.f;
        float sn,cs; sincosf(PI2*(float)((w*k)%NW)/(float)NW,&sn,&cs);
        v = ck*(im? -sn : cs)*SC_W;
      }
    }
    ((ushort*)(ws+OFF_TWI))[t]=f2us(v); return;
  } t-=65536;
  if (t < 65536){ int o=t>>8,i=t&255; ((ushort*)(ws+OFF_WRT))[t]=f2us(wsr[i*NC+o]); return; } t-=65536;
  if (t < 65536){ int o=t>>8,i=t&255; ((ushort*)(ws+OFF_WIT))[t]=f2us(wsi[i*NC+o]); return; } t-=65536;
  if (t < 65536){ ((ushort*)(ws+OFF_IWB))[t]=f2us(iw[t]); return; } t-=65536;
  if (t < 131072){ ((ushort*)(ws+OFF_W2B))[t]=f2us(w2[t]); return; }
}

// ---------------- instance-norm stats on x ----------------
__global__ __launch_bounds__(256) void k_stats0(const float* x, const float* n0w, const float* n0b, float* ws){
  int g = blockIdx.x, c = g & (NC-1);
  const float4* xp = (const float4*)(x + (size_t)g*NHW);
  float s=0.f, q=0.f;
  for(int i=threadIdx.x;i<NHW/4;i+=256){
    float4 v=xp[i];
    s+=v.x+v.y+v.z+v.w;
    q=fmaf(v.x,v.x,fmaf(v.y,v.y,fmaf(v.z,v.z,fmaf(v.w,v.w,q))));
  }
  __shared__ float ls[4], lq[4];
  #pragma unroll
  for(int o=32;o>0;o>>=1){ s+=__shfl_down(s,o,64); q+=__shfl_down(q,o,64); }
  int lane=threadIdx.x&63, wid=threadIdx.x>>6;
  if(!lane){ ls[wid]=s; lq[wid]=q; }
  __syncthreads();
  if(!threadIdx.x){
    s=ls[0]+ls[1]+ls[2]+ls[3]; q=lq[0]+lq[1]+lq[2]+lq[3];
    float m=s*(1.f/NHW), var=q*(1.f/NHW)-m*m;
    float r=rsqrtf(var+REPS);
    float a=r*n0w[c];
    ws[OFF_A0+g]=a; ws[OFF_D0+g]=fmaf(-m,a,n0b[c]);
  }
}

// ---------------- norm+cast: x -> A1 bf16 [g][h][256] ----------------
__global__ __launch_bounds__(256) void k_norm(const float* x, float* ws){
  int h = blockIdx.x, g = blockIdx.y, t = threadIdx.x;
  float a = ws[OFF_A0+g], d = ws[OFF_D0+g];
  ushort v = 0;
  if(t < NW) v = f2us(fmaf(a, x[(size_t)g*NHW + (size_t)h*NW + t], d));
  ((ushort*)(ws+RA0))[(size_t)g*30720 + (size_t)h*256 + t] = v;
}

// ---------------- spectral GEMM ----------------
template<int SPLIT, int EPI>
__global__ __launch_bounds__(256) void k_sgemm(const ushort* Ap0, const ushort* Ap1, const ushort* Bm,
                                               ushort* O0, ushort* O1, ushort* Ub){
  int nb = blockIdx.x*64, mb = blockIdx.y*256;
  int tid = threadIdx.x, w = tid>>6, l = tid&63, lq = l>>4, lr = l&15;
  const ushort* ar0[4]; const ushort* ar1[4]; const ushort* br[4];
  #pragma unroll
  for(int mt=0;mt<4;mt++){
    size_t r = mb + w*64 + mt*16 + lr;
    ar0[mt] = Ap0 + r*(SPLIT?128:256) + lq*8;
    ar1[mt] = SPLIT ? (Ap1 + r*128 + lq*8) : ar0[mt];
  }
  #pragma unroll
  for(int nt=0;nt<4;nt++) br[nt] = Bm + (size_t)(nb + nt*16 + lr)*256 + lq*8;
  f32x4 acc[4][4] = {};
  #pragma unroll
  for(int kk=0;kk<8;kk++){
    int k = kk*32;
    short8 af[4], bfr[4];
    #pragma unroll
    for(int mt=0;mt<4;mt++){
      const ushort* p = SPLIT ? ((k<128 ? ar0[mt] : ar1[mt]) + (k&127)) : (ar0[mt] + k);
      af[mt] = *(const short8*)p;
    }
    #pragma unroll
    for(int nt=0;nt<4;nt++) bfr[nt] = *(const short8*)(br[nt]+k);
    #pragma unroll
    for(int mt=0;mt<4;mt++)
      #pragma unroll
      for(int nt=0;nt<4;nt++)
        acc[mt][nt] = __builtin_amdgcn_mfma_f32_16x16x32_bf16(af[mt], bfr[nt], acc[mt][nt], 0,0,0);
  }
  #pragma unroll
  for(int mt=0;mt<4;mt++){
    #pragma unroll
    for(int r=0;r<4;r++){
      int m = mb + w*64 + mt*16 + lq*4 + r;
      #pragma unroll
      for(int nt=0;nt<4;nt++){
        int n = nb + nt*16 + lr;
        float v = acc[mt][nt][r];
        if (EPI==0){
          if(n<128) O0[(size_t)m*128+n] = f2us(v);
          else      O1[(size_t)m*128+n-128] = f2us(v);
        } else {
          int g = m>>7, h = m&127;
          if(h<NH && n<NW) Ub[(size_t)g*NHW + (size_t)h*NW + n] = f2us(v);
        }
      }
    }
  }
}

// ---------------- 64x64 bf16 transpose within 128-stride planes ----------------
__global__ __launch_bounds__(256) void k_t64(const ushort* src, ushort* dst, int srows, int sgstr){
  __shared__ ushort lt[64][72];
  int g=blockIdx.z, i0=blockIdx.y*64, p0=blockIdx.x*64;
  int t=threadIdx.x, r=t>>2, q=t&3;
  int row = i0 + r;
  uint4 u0=make_uint4(0,0,0,0), u1=u0;
  if(row < srows){
    const ushort* sp = src + (size_t)g*sgstr + (size_t)row*128 + p0 + q*16;
    u0=*(const uint4*)sp; u1=*(const uint4*)(sp+8);
  }
  *(uint4*)&lt[r][q*16]=u0; *(uint4*)&lt[r][q*16+8]=u1;
  __syncthreads();
  int pr=t>>2, q2=t&3;
  union { ushort s[8]; uint4 u; } o0, o1;
  #pragma unroll
  for(int e=0;e<8;e++){ o0.s[e]=lt[q2*16+e][pr]; o1.s[e]=lt[q2*16+8+e][pr]; }
  ushort* dp = dst + (size_t)g*NSP + (size_t)(p0+pr)*128 + i0 + q2*16;
  *(uint4*)dp = o0.u; *(uint4*)(dp+8) = o1.u;
}

// ---------------- pixel transpose: [b][c:256][NSP] -> [b][NSP][c] ----------------
__global__ __launch_bounds__(256) void k_tP(const ushort* src, ushort* dst){
  __shared__ ushort lt[64][72];
  int b=blockIdx.z, i0=blockIdx.y*64, p0=blockIdx.x*64;
  int t=threadIdx.x, r=t>>2, q=t&3;
  const ushort* sp = src + (size_t)(b*NC+i0+r)*NSP + p0 + q*16;
  uint4 u0=*(const uint4*)sp, u1=*(const uint4*)(sp+8);
  *(uint4*)&lt[r][q*16]=u0; *(uint4*)&lt[r][q*16+8]=u1;
  __syncthreads();
  int pr=t>>2, q2=t&3;
  union { ushort s[8]; uint4 u; } o0, o1;
  #pragma unroll
  for(int e=0;e<8;e++){ o0.s[e]=lt[q2*16+e][pr]; o1.s[e]=lt[q2*16+8+e][pr]; }
  ushort* dp = dst + ((size_t)b*NSP + p0 + pr)*NC + i0 + q2*16;
  *(uint4*)dp = o0.u; *(uint4*)(dp+8) = o1.u;
}

// ---------------- complex spectral mix via MFMA ----------------
__global__ __launch_bounds__(256) void k_mixg(float* ws){
  int b = blockIdx.z, p0 = blockIdx.x*32;
  int tid = threadIdx.x, w = tid>>6, l = tid&63, lq = l>>4, lr = l&15;
  const ushort* Wr = (const ushort*)(ws+OFF_WRT);
  const ushort* Wi = (const ushort*)(ws+OFF_WIT);
  const ushort* Gr = (const ushort*)(ws+RA0) + (size_t)b*NSP*NC;
  const ushort* Gi = (const ushort*)(ws+RA1) + (size_t)b*NSP*NC;
  const ushort *wrr[4], *wir[4], *brr[2], *bir[2];
  #pragma unroll
  for(int mt=0;mt<4;mt++){ size_t ro=(size_t)(w*64+mt*16+lr)*NC+lq*8; wrr[mt]=Wr+ro; wir[mt]=Wi+ro; }
  #pragma unroll
  for(int nt=0;nt<2;nt++){ size_t ro=(size_t)(p0+nt*16+lr)*NC+lq*8; brr[nt]=Gr+ro; bir[nt]=Gi+ro; }
  f32x4 aR[4][2]={}, aI[4][2]={};
  for(int k=0;k<256;k+=32){
    short8 fr[4], fi[4], fin[4], gr[2], gi[2];
    #pragma unroll
    for(int mt=0;mt<4;mt++){
      fr[mt]=*(const short8*)(wrr[mt]+k);
      fi[mt]=*(const short8*)(wir[mt]+k);
      union { short8 s; uint u[4]; } nv; nv.s=fi[mt];
      nv.u[0]^=0x80008000u; nv.u[1]^=0x80008000u; nv.u[2]^=0x80008000u; nv.u[3]^=0x80008000u;
      fin[mt]=nv.s;
    }
    #pragma unroll
    for(int nt=0;nt<2;nt++){ gr[nt]=*(const short8*)(brr[nt]+k); gi[nt]=*(const short8*)(bir[nt]+k); }
    #pragma unroll
    for(int mt=0;mt<4;mt++)
      #pragma unroll
      for(int nt=0;nt<2;nt++){
        aR[mt][nt]=__builtin_amdgcn_mfma_f32_16x16x32_bf16(fr[mt], gr[nt], aR[mt][nt],0,0,0);
        aR[mt][nt]=__builtin_amdgcn_mfma_f32_16x16x32_bf16(fin[mt],gi[nt], aR[mt][nt],0,0,0);
        aI[mt][nt]=__builtin_amdgcn_mfma_f32_16x16x32_bf16(fi[mt], gr[nt], aI[mt][nt],0,0,0);
        aI[mt][nt]=__builtin_amdgcn_mfma_f32_16x16x32_bf16(fr[mt], gi[nt], aI[mt][nt],0,0,0);
      }
  }
  ushort* Yre = (ushort*)(ws+RB0);
  ushort* Yim = (ushort*)(ws+RB1);
  #pragma unroll
  for(int mt=0;mt<4;mt++){
    #pragma unroll
    for(int r=0;r<4;r++){
      int m = w*64 + mt*16 + lq*4 + r;
      #pragma unroll
      for(int nt=0;nt<2;nt++){
        int n = p0 + nt*16 + lr;
        size_t ad = (size_t)(b*NC+m)*NSP + n;
        Yre[ad] = f2us(aR[mt][nt][r]);
        Yim[ad] = f2us(aI[mt][nt][r]);
      }
    }
  }
}

// ---------------- Phase A: fused x-transpose + inner conv + gelu + stats + U' ----------------
__global__ __launch_bounds__(256,2) void k_inner(float* ws, const float* x, const float* ib){
  __shared__ ushort xt[64][264];
  int b = blockIdx.z, blk = blockIdx.x, p0 = blk*64;
  int t = threadIdx.x, w = t>>6, l = t&63, lq = l>>4, lr = l&15;
  // load + transpose x tile -> xt[p][c] bf16
  #pragma unroll 4
  for(int cc=0; cc<16; cc++){
    int c = cc*16 + (t>>4);
    int p4 = (t&15)*4;
    float4 v = *(const float4*)(x + ((size_t)(b*NC+c))*NHW + p0 + p4);
    xt[p4  ][c]=f2us(v.x); xt[p4+1][c]=f2us(v.y);
    xt[p4+2][c]=f2us(v.z); xt[p4+3][c]=f2us(v.w);
  }
  __syncthreads();
  const ushort* W = (const ushort*)(ws+OFF_IWB);
  const ushort* ar[4];
  #pragma unroll
  for(int mt=0;mt<4;mt++) ar[mt] = W + (size_t)(w*64+mt*16+lr)*256 + lq*8;
  f32x4 acc[4][4] = {};
  #pragma unroll
  for(int kk=0;kk<8;kk++){
    int k = kk*32;
    short8 af[4], bfr[4];
    #pragma unroll
    for(int mt=0;mt<4;mt++) af[mt] = *(const short8*)(ar[mt]+k);
    #pragma unroll
    for(int nt=0;nt<4;nt++) bfr[nt] = *(const short8*)&xt[nt*16+lr][k+lq*8];
    #pragma unroll
    for(int mt=0;mt<4;mt++)
      #pragma unroll
      for(int nt=0;nt<4;nt++)
        acc[mt][nt] = __builtin_amdgcn_mfma_f32_16x16x32_bf16(af[mt], bfr[nt], acc[mt][nt], 0,0,0);
  }
  __syncthreads();   // all waves done reading xt; reuse as output transpose buffer
  const ushort* Usp = (const ushort*)(ws+OFF_RA);
  float* PS = ws + OFF_PS + ((size_t)(b*NPT+blk))*512;
  #pragma unroll
  for(int mt=0;mt<4;mt++){
    #pragma unroll
    for(int r=0;r<4;r++){
      int m = w*64 + mt*16 + lq*4 + r;
      float bb = ib[m];
      float ss = 0.f, sq = 0.f;
      #pragma unroll
      for(int nt=0;nt<4;nt++){
        int n = p0 + nt*16 + lr;
        float uv = us2f(Usp[((size_t)(b*NC+m))*NHW + n]);
        float g = gelu_f(acc[mt][nt][r] + bb + uv);
        xt[nt*16+lr][m] = f2us(g);
        ss += g; sq = fmaf(g,g,sq);
      }
      #pragma unroll
      for(int ofs=1; ofs<16; ofs<<=1){ ss += __shfl_xor(ss, ofs, 64); sq += __shfl_xor(sq, ofs, 64); }
      if(lr==0){ PS[m] = ss; PS[256+m] = sq; }
    }
  }
  __syncthreads();
  ushort* Up = (ushort*)(ws+OFF_RB);
  #pragma unroll
  for(int pp=0; pp<4; pp++){
    int p = pp*16 + (t>>4);
    int c0 = (t&15)*16;
    uint4 w0 = *(uint4*)&xt[p][c0];
    uint4 w1v = *(uint4*)&xt[p][c0+8];
    ushort* dp = Up + ((size_t)(b*NHW + p0 + p))*256 + c0;
    *(uint4*)dp = w0; *(uint4*)(dp+8) = w1v;
  }
}

// ---------------- stats1: reduce partials -> a1,d1 (FiLM folded) ----------------
__global__ __launch_bounds__(256) void k_stats1p(const float* gamma, const float* beta,
                                                 const float* n1w, const float* n1b, float* ws){
  int g = blockIdx.x, b = g>>8, c = g&255;
  float s=0.f, q=0.f;
  for(int i=threadIdx.x;i<NPT;i+=256){
    const float* P = ws + OFF_PS + ((size_t)(b*NPT+i))*512;
    s += P[c]; q += P[256+c];
  }
  __shared__ float ls[4], lq2[4];
  #pragma unroll
  for(int o=32;o>0;o>>=1){ s+=__shfl_down(s,o,64); q+=__shfl_down(q,o,64); }
  int lane=threadIdx.x&63, wid=threadIdx.x>>6;
  if(!lane){ ls[wid]=s; lq2[wid]=q; }
  __syncthreads();
  if(!threadIdx.x){
    s=ls[0]+ls[1]+ls[2]+ls[3]; q=lq2[0]+lq2[1]+lq2[2]+lq2[3];
    float m=s*(1.f/NHW), var=q*(1.f/NHW)-m*m;
    float r=rsqrtf(var+REPS);
    float gp1 = 1.f + gamma[c];
    float wv = n1w[c];
    ws[OFF_A1c+g] = gp1*wv*r;
    ws[OFF_D1c+g] = gp1*(n1b[c] - m*r*wv) + beta[c];
  }
}

// ---------------- fold a1/d1 into W1: W1'[b]=W1*diag(a1), b1'=W1*d1+b1 ----------------
__global__ __launch_bounds__(64) void k_fold(float* ws, const float* w1, const float* b1){
  int o = blockIdx.x, b = blockIdx.y, t = threadIdx.x;
  float acc = 0.f;
  ushort* W1p = (ushort*)(ws+OFF_W1P);
  #pragma unroll
  for(int ii=0; ii<4; ii++){
    int i = ii*64 + t;
    float wv = w1[o*256+i];
    W1p[((size_t)(b*NHID+o))*256 + i] = f2us(wv * ws[OFF_A1c + b*NC + i]);
    acc = fmaf(wv, ws[OFF_D1c + b*NC + i], acc);
  }
  #pragma unroll
  for(int ofs=32; ofs; ofs>>=1) acc += __shfl_down(acc, ofs, 64);
  if(!t) ws[OFF_B1P + b*NHID + o] = acc + b1[o];
}

// ---------------- Phase C: fused mlp1+gelu+mlp2+residual ----------------
__global__ __launch_bounds__(256,2) void k_mlp(float* ws, const float* x, const float* b2, float* out){
  __shared__ ushort midT[64][520];
  int b = blockIdx.z, p0 = blockIdx.x*64;
  int t = threadIdx.x, w = t>>6, l = t&63, lq = l>>4, lr = l&15;
  const ushort* W1p = (const ushort*)(ws+OFF_W1P) + (size_t)b*NHID*256;
  const ushort* Up  = (const ushort*)(ws+OFF_RB);
  const ushort* ar[8]; const ushort* br[4];
  #pragma unroll
  for(int mt=0;mt<8;mt++) ar[mt] = W1p + (size_t)(w*128+mt*16+lr)*256 + lq*8;
  #pragma unroll
  for(int nt=0;nt<4;nt++) br[nt] = Up + ((size_t)(b*NHW + p0 + nt*16+lr))*256 + lq*8;
  f32x4 acc1[8][4] = {};
  #pragma unroll
  for(int kk=0;kk<8;kk++){
    int k = kk*32;
    short8 bfr[4];
    #pragma unroll
    for(int nt=0;nt<4;nt++) bfr[nt] = *(const short8*)(br[nt]+k);
    #pragma unroll
    for(int mt=0;mt<8;mt++){
      short8 af = *(const short8*)(ar[mt]+k);
      #pragma unroll
      for(int nt=0;nt<4;nt++)
        acc1[mt][nt] = __builtin_amdgcn_mfma_f32_16x16x32_bf16(af, bfr[nt], acc1[mt][nt], 0,0,0);
    }
  }
  const float* b1p = ws + OFF_B1P + b*NHID;
  #pragma unroll
  for(int mt=0;mt<8;mt++){
    #pragma unroll
    for(int r=0;r<4;r++){
      int m1 = w*128 + mt*16 + lq*4 + r;
      float bb = b1p[m1];
      #pragma unroll
      for(int nt=0;nt<4;nt++){
        int p = nt*16 + lr;
        midT[p][m1] = f2us(gelu_f(acc1[mt][nt][r] + bb));
      }
    }
  }
  __syncthreads();
  const ushort* W2 = (const ushort*)(ws+OFF_W2B);
  const ushort* a2[4];
  #pragma unroll
  for(int mt=0;mt<4;mt++) a2[mt] = W2 + (size_t)(w*64+mt*16+lr)*512 + lq*8;
  f32x4 acc2[4][4] = {};
  #pragma unroll
  for(int kk=0;kk<16;kk++){
    int k = kk*32;
    short8 af[4], bfr[4];
    #pragma unroll
    for(int mt=0;mt<4;mt++) af[mt] = *(const short8*)(a2[mt]+k);
    #pragma unroll
    for(int nt=0;nt<4;nt++) bfr[nt] = *(const short8*)&midT[nt*16+lr][k+lq*8];
    #pragma unroll
    for(int mt=0;mt<4;mt++)
      #pragma unroll
      for(int nt=0;nt<4;nt++)
        acc2[mt][nt] = __builtin_amdgcn_mfma_f32_16x16x32_bf16(af[mt], bfr[nt], acc2[mt][nt], 0,0,0);
  }
  #pragma unroll
  for(int mt=0;mt<4;mt++){
    #pragma unroll
    for(int r=0;r<4;r++){
      int om = w*64 + mt*16 + lq*4 + r;
      float bb = b2[om];
      #pragma unroll
      for(int nt=0;nt<4;nt++){
        int n = p0 + nt*16 + lr;
        size_t ad = ((size_t)(b*NC+om))*NHW + n;
        out[ad] = acc2[mt][nt][r] + bb + x[ad];
      }
    }
  }
}

extern "C" void kernel_launch(void* const* d_in, const int* in_sizes, int n_in,
                              void* d_out, int out_size, void* d_ws, size_t ws_size,
                              hipStream_t stream) {
  const float* x     = (const float*)d_in[0];
  const float* gamma = (const float*)d_in[1];
  const float* beta  = (const float*)d_in[2];
  const float* n0w   = (const float*)d_in[3];
  const float* n0b   = (const float*)d_in[4];
  const float* n1w   = (const float*)d_in[5];
  const float* n1b   = (const float*)d_in[6];
  const float* wsr   = (const float*)d_in[7];
  const float* wsi   = (const float*)d_in[8];
  const float* iw    = (const float*)d_in[9];
  const float* ib    = (const float*)d_in[10];
  const float* w1    = (const float*)d_in[11];
  const float* b1    = (const float*)d_in[12];
  const float* w2    = (const float*)d_in[13];
  const float* b2    = (const float*)d_in[14];
  float* ws = (float*)d_ws;
  float* out = (float*)d_out;
  if (ws_size < WS_FLOATS*4ULL) return;

  k_setup <<<dim3(2304), dim3(256), 0, stream>>>(ws, wsr, wsi, iw, w2);
  k_stats0<<<dim3(512),  dim3(256), 0, stream>>>(x, n0w, n0b, ws);
  k_norm  <<<dim3(120,512), dim3(256), 0, stream>>>(x, ws);
  // GEMM1: A1(RA) -> F(RB planes)
  k_sgemm<0,0><<<dim3(4,240), dim3(256), 0, stream>>>((const ushort*)(ws+RA0), (const ushort*)(ws+RA0),
      (const ushort*)(ws+OFF_TWF), (ushort*)(ws+OFF_FRE), (ushort*)(ws+OFF_FIM), nullptr);
  // T1: F(RB) -> Ft(RA)
  k_t64 <<<dim3(2,2,512), dim3(256), 0, stream>>>((const ushort*)(ws+OFF_FRE), (ushort*)(ws+RA0), NH, NH*128);
  k_t64 <<<dim3(2,2,512), dim3(256), 0, stream>>>((const ushort*)(ws+OFF_FIM), (ushort*)(ws+RA1), NH, NH*128);
  // GEMM2: Ft(RA) -> G(RB)
  k_sgemm<1,0><<<dim3(4,256), dim3(256), 0, stream>>>((const ushort*)(ws+RA0), (const ushort*)(ws+RA1),
      (const ushort*)(ws+OFF_THF), (ushort*)(ws+RB0), (ushort*)(ws+RB1), nullptr);
  // T2: G(RB) -> Gt(RA) [b][p][c]
  k_tP <<<dim3(256,4,2), dim3(256), 0, stream>>>((const ushort*)(ws+RB0), (ushort*)(ws+RA0));
  k_tP <<<dim3(256,4,2), dim3(256), 0, stream>>>((const ushort*)(ws+RB1), (ushort*)(ws+RA1));
  // mix: Gt(RA) -> Y(RB)
  k_mixg <<<dim3(512,1,2), dim3(256), 0, stream>>>(ws);
  // GEMM4: Y(RB) -> Z(RA)
  k_sgemm<1,0><<<dim3(4,256), dim3(256), 0, stream>>>((const ushort*)(ws+RB0), (const ushort*)(ws+RB1),
      (const ushort*)(ws+OFF_THI), (ushort*)(ws+RA0), (ushort*)(ws+RA1), nullptr);
  // T3: Z(RA) -> Zt(RB)
  k_t64 <<<dim3(2,2,512), dim3(256), 0, stream>>>((const ushort*)(ws+RA0), (ushort*)(ws+RB0), 128, NSP);
  k_t64 <<<dim3(2,2,512), dim3(256), 0, stream>>>((const ushort*)(ws+RA1), (ushort*)(ws+RB1), 128, NSP);
  // GEMM5: Zt(RB) -> U spectral bf16 channel-major (RA)
  k_sgemm<1,1><<<dim3(4,256), dim3(256), 0, stream>>>((const ushort*)(ws+RB0), (const ushort*)(ws+RB1),
      (const ushort*)(ws+OFF_TWI), nullptr, nullptr, (ushort*)(ws+RA0));
  // Phase A: inner conv fused (x + Usp -> U' pixel-major bf16 in RB, + stats partials)
  k_inner <<<dim3(NPT,1,2), dim3(256), 0, stream>>>(ws, x, ib);
  k_stats1p<<<dim3(512), dim3(256), 0, stream>>>(gamma, beta, n1w, n1b, ws);
  k_fold  <<<dim3(512,2), dim3(64), 0, stream>>>(ws, w1, b1);
  // Phase C: fused MLP
  k_mlp   <<<dim3(NPT,1,2), dim3(256), 0, stream>>>(ws, x, b2, out);
}